// Round 1
// baseline (434.442 us; speedup 1.0000x reference)
//
#include <hip/hip_runtime.h>

// ---------- types ----------
typedef _Float16 h16;
typedef _Float16 h16x8 __attribute__((ext_vector_type(8)));
typedef _Float16 h16x4 __attribute__((ext_vector_type(4)));
typedef float    f32x4 __attribute__((ext_vector_type(4)));
typedef unsigned int u32x4 __attribute__((ext_vector_type(4)));

// Problem constants: B=16 batches, Lrows=1024 (256 target + 768 claim), F=256.
#define NBATCH 16
#define LROWS  1024
#define FDIM   256

// d_out element offsets (fp32 elements)
#define OFF_TGT 0ull
#define OFF_CLM 1048576ull
#define OFF_NR  4194304ull     // + layer*4194304
#define OFF_AT  16777216ull    // + layer*16777216

__device__ __forceinline__ void split2(float x, h16& h, h16& l) {
    h = (h16)x;
    l = (h16)(x - (float)h);   // Sterbenz-exact residual, then RNE to fp16
}

// ---------- init: concat(target,claim) -> x hi/lo fp16 ----------
__global__ __launch_bounds__(256) void convert_x(const float* __restrict__ tgt,
                                                 const float* __restrict__ clm,
                                                 h16* __restrict__ xh, h16* __restrict__ xl) {
    size_t i4 = (size_t)blockIdx.x * 256 + threadIdx.x;   // 4096 blocks
    size_t e  = i4 * 4;                                   // element index in [16][1024][256]
    int b  = (int)(e >> 18);
    int rf = (int)(e & 262143);
    int r  = rf >> 8, f = rf & 255;
    const float* src = (r < 256)
        ? tgt + ((size_t)b << 16) + ((size_t)r << 8) + f
        : clm + (size_t)b * 196608 + ((size_t)(r - 256) << 8) + f;
    f32x4 v = *(const f32x4*)src;
    h16x4 hv, lv;
#pragma unroll
    for (int j = 0; j < 4; ++j) { h16 hh, ll; split2(v[j], hh, ll); hv[j] = hh; lv[j] = ll; }
    *(h16x4*)(xh + e) = hv;
    *(h16x4*)(xl + e) = lv;
}

__global__ __launch_bounds__(256) void convert_w(const float* __restrict__ W,
                                                 h16* __restrict__ wh, h16* __restrict__ wl) {
    size_t e = ((size_t)blockIdx.x * 256 + threadIdx.x) * 4;   // 192 blocks -> 3*256*256
    f32x4 v = *(const f32x4*)(W + e);
    h16x4 hv, lv;
#pragma unroll
    for (int j = 0; j < 4; ++j) { h16 hh, ll; split2(v[j], hh, ll); hv[j] = hh; lv[j] = ll; }
    *(h16x4*)(wh + e) = hv;
    *(h16x4*)(wl + e) = lv;
}

// ---------- split-fp16 GEMM: C[M=1024 x N] = A · B^T, K=256 ----------
// MODE 0 (corr): N=1024, B = x (per batch), C fp32 -> d_out attn slot (raw logits)
// MODE 1 (trans): N=256,  B = W (per layer), store transposed hi/lo fp16 (transT[g][l])
template <int MODE>
__global__ __launch_bounds__(256, 2) void gemm_split(
    const h16* __restrict__ Ah, const h16* __restrict__ Al,
    const h16* __restrict__ Bh, const h16* __restrict__ Bl,
    float* __restrict__ C, h16* __restrict__ Th, h16* __restrict__ Tl) {
    constexpr int K    = 256;
    constexpr int NTOT = (MODE == 0) ? 1024 : 256;
    const int b  = blockIdx.z;
    const int i0 = blockIdx.y * 128;
    const int j0 = blockIdx.x * 128;
    const int t  = threadIdx.x;
    const int lane = t & 63, wid = t >> 6;
    const int wr = wid >> 1, wc = wid & 1;

    __shared__ alignas(16) char lds[65536];  // Ah 0 | Al 16K | Bh 32K | Bl 48K

    const size_t abase = ((size_t)b * LROWS + i0) * K;
    const size_t bbase = ((size_t)((MODE == 0) ? b : 0) * NTOT + j0) * K;

    f32x4 acc[4][4];
#pragma unroll
    for (int i = 0; i < 4; ++i)
#pragma unroll
        for (int j = 0; j < 4; ++j) acc[i][j] = (f32x4){0.f, 0.f, 0.f, 0.f};

    for (int kt = 0; kt < K / 64; ++kt) {
        const h16* aH = Ah + abase + kt * 64;
        const h16* aL = Al + abase + kt * 64;
        const h16* bH = Bh + bbase + kt * 64;
        const h16* bL = Bl + bbase + kt * 64;
        u32x4 vAh[4], vAl[4], vBh[4], vBl[4];
#pragma unroll
        for (int it = 0; it < 4; ++it) {
            int row = it * 32 + (t >> 3);
            int q   = t & 7;
            size_t go = (size_t)row * K + q * 8;
            vAh[it] = *(const u32x4*)(aH + go);
            vAl[it] = *(const u32x4*)(aL + go);
            vBh[it] = *(const u32x4*)(bH + go);
            vBl[it] = *(const u32x4*)(bL + go);
        }
        __syncthreads();   // prior compute done reading LDS
#pragma unroll
        for (int it = 0; it < 4; ++it) {
            int row = it * 32 + (t >> 3);
            int p   = (t & 7) ^ (row & 7);      // XOR swizzle
            int off = row * 128 + p * 16;
            *(u32x4*)(lds + off)         = vAh[it];
            *(u32x4*)(lds + 16384 + off) = vAl[it];
            *(u32x4*)(lds + 32768 + off) = vBh[it];
            *(u32x4*)(lds + 49152 + off) = vBl[it];
        }
        __syncthreads();

        const int kq = lane >> 4;
        const int rA = wr * 64 + (lane & 15);
        const int rB = wc * 64 + (lane & 15);
#pragma unroll
        for (int s = 0; s < 2; ++s) {
            h16x8 ah[4], al[4], bh[4], bl[4];
#pragma unroll
            for (int mi = 0; mi < 4; ++mi) {
                int r   = rA + mi * 16;
                int off = r * 128 + (((s * 4 + kq) ^ (r & 7)) * 16);
                ah[mi] = *(const h16x8*)(lds + off);
                al[mi] = *(const h16x8*)(lds + 16384 + off);
            }
#pragma unroll
            for (int nj = 0; nj < 4; ++nj) {
                int r   = rB + nj * 16;
                int off = r * 128 + (((s * 4 + kq) ^ (r & 7)) * 16);
                bh[nj] = *(const h16x8*)(lds + 32768 + off);
                bl[nj] = *(const h16x8*)(lds + 49152 + off);
            }
#pragma unroll
            for (int mi = 0; mi < 4; ++mi)
#pragma unroll
                for (int nj = 0; nj < 4; ++nj) {
                    acc[mi][nj] = __builtin_amdgcn_mfma_f32_16x16x32_f16(ah[mi], bh[nj], acc[mi][nj], 0, 0, 0);
                    acc[mi][nj] = __builtin_amdgcn_mfma_f32_16x16x32_f16(ah[mi], bl[nj], acc[mi][nj], 0, 0, 0);
                    acc[mi][nj] = __builtin_amdgcn_mfma_f32_16x16x32_f16(al[mi], bh[nj], acc[mi][nj], 0, 0, 0);
                }
        }
    }

    const int mBase = i0 + wr * 64;
    const int nBase = j0 + wc * 64;
    if constexpr (MODE == 0) {
        float* Cb = C + (size_t)b * LROWS * 1024;
#pragma unroll
        for (int mi = 0; mi < 4; ++mi)
#pragma unroll
            for (int nj = 0; nj < 4; ++nj) {
                int n  = nBase + nj * 16 + (lane & 15);
                int m0 = mBase + mi * 16 + ((lane >> 4) * 4);
#pragma unroll
                for (int rg = 0; rg < 4; ++rg)
                    Cb[(size_t)(m0 + rg) * 1024 + n] = acc[mi][nj][rg];
            }
    } else {
#pragma unroll
        for (int mi = 0; mi < 4; ++mi)
#pragma unroll
            for (int nj = 0; nj < 4; ++nj) {
                int n  = nBase + nj * 16 + (lane & 15);
                int m0 = mBase + mi * 16 + ((lane >> 4) * 4);
                h16x4 hv, lv;
#pragma unroll
                for (int rg = 0; rg < 4; ++rg) { h16 hh, ll; split2(acc[mi][nj][rg], hh, ll); hv[rg] = hh; lv[rg] = ll; }
                size_t off = ((size_t)b * 256 + n) * 1024 + m0;  // transT[b][g][l]
                *(h16x4*)(Th + off) = hv;
                *(h16x4*)(Tl + off) = lv;
            }
    }
}

// ---------- fused one-pass row softmax, in place over [16*1024][1024] fp32 ----------
__global__ __launch_bounds__(256) void softmax_rows(float* __restrict__ at) {
    float* p = at + (size_t)blockIdx.x * 1024;
    const int t = threadIdx.x;
    f32x4 v = *(const f32x4*)(p + t * 4);
    float m = fmaxf(fmaxf(v[0], v[1]), fmaxf(v[2], v[3]));
#pragma unroll
    for (int off = 32; off >= 1; off >>= 1) m = fmaxf(m, __shfl_xor(m, off, 64));
    __shared__ float red[8];
    const int lane = t & 63, wid = t >> 6;
    if (lane == 0) red[wid] = m;
    __syncthreads();
    m = fmaxf(fmaxf(red[0], red[1]), fmaxf(red[2], red[3]));
    f32x4 e;
    e[0] = __expf(v[0] - m); e[1] = __expf(v[1] - m);
    e[2] = __expf(v[2] - m); e[3] = __expf(v[3] - m);
    float s = e[0] + e[1] + e[2] + e[3];
#pragma unroll
    for (int off = 32; off >= 1; off >>= 1) s += __shfl_xor(s, off, 64);
    if (lane == 0) red[4 + wid] = s;
    __syncthreads();
    s = red[4] + red[5] + red[6] + red[7];
    float inv = 1.0f / s;
    e[0] *= inv; e[1] *= inv; e[2] *= inv; e[3] *= inv;
    *(f32x4*)(p + t * 4) = e;
}

// ---------- PV: Node = relu(x + attn·trans); writes fp32 node_rep + new x hi/lo ----------
// M=1024 (i), N=256 (g), K=1024 (j). A = attn fp32 (split on the fly), B = transT hi/lo.
__global__ __launch_bounds__(256, 2) void gemm_pv(
    const float* __restrict__ Attn,
    const h16* __restrict__ Th, const h16* __restrict__ Tl,
    h16* __restrict__ Xh, h16* __restrict__ Xl,
    float* __restrict__ NodeOut) {
    const int b  = blockIdx.z;
    const int i0 = blockIdx.y * 128;
    const int n0 = blockIdx.x * 128;
    const int t  = threadIdx.x;
    const int lane = t & 63, wid = t >> 6;
    const int wr = wid >> 1, wc = wid & 1;

    __shared__ alignas(16) char lds[65536];  // A f32 [128][64] 32K | Bh 16K | Bl 16K

    f32x4 acc[4][4];
#pragma unroll
    for (int i = 0; i < 4; ++i)
#pragma unroll
        for (int j = 0; j < 4; ++j) acc[i][j] = (f32x4){0.f, 0.f, 0.f, 0.f};

    const float* Ab  = Attn + ((size_t)b * LROWS + i0) * 1024;
    const size_t bbase = ((size_t)b * 256 + n0) * 1024;

    for (int kt = 0; kt < 16; ++kt) {
        f32x4 va[8]; u32x4 vbh[4], vbl[4];
#pragma unroll
        for (int it = 0; it < 8; ++it) {
            int row = it * 16 + (t >> 4);
            int q   = t & 15;
            va[it] = *(const f32x4*)(Ab + (size_t)row * 1024 + kt * 64 + q * 4);
        }
#pragma unroll
        for (int it = 0; it < 4; ++it) {
            int row = it * 32 + (t >> 3);
            int q   = t & 7;
            size_t go = (size_t)row * 1024 + kt * 64 + q * 8;
            vbh[it] = *(const u32x4*)(Th + bbase + go);
            vbl[it] = *(const u32x4*)(Tl + bbase + go);
        }
        __syncthreads();
#pragma unroll
        for (int it = 0; it < 8; ++it) {
            int row = it * 16 + (t >> 4);
            int p   = (t & 15) ^ (row & 15);
            *(f32x4*)(lds + row * 256 + p * 16) = va[it];
        }
#pragma unroll
        for (int it = 0; it < 4; ++it) {
            int row = it * 32 + (t >> 3);
            int p   = (t & 7) ^ (row & 7);
            int off = row * 128 + p * 16;
            *(u32x4*)(lds + 32768 + off) = vbh[it];
            *(u32x4*)(lds + 49152 + off) = vbl[it];
        }
        __syncthreads();

        const int kq = lane >> 4;
        const int rA = wr * 64 + (lane & 15);
        const int rB = wc * 64 + (lane & 15);
#pragma unroll
        for (int s = 0; s < 2; ++s) {
            h16x8 ah[4], al[4], bh[4], bl[4];
#pragma unroll
            for (int mi = 0; mi < 4; ++mi) {
                int r  = rA + mi * 16;
                int lc = s * 8 + kq * 2;
                f32x4 u0 = *(const f32x4*)(lds + r * 256 + (((lc)     ^ (r & 15)) * 16));
                f32x4 u1 = *(const f32x4*)(lds + r * 256 + (((lc + 1) ^ (r & 15)) * 16));
                h16x8 hh, ll;
#pragma unroll
                for (int e = 0; e < 4; ++e) { h16 h_, l_; split2(u0[e], h_, l_); hh[e] = h_;     ll[e] = l_; }
#pragma unroll
                for (int e = 0; e < 4; ++e) { h16 h_, l_; split2(u1[e], h_, l_); hh[4 + e] = h_; ll[4 + e] = l_; }
                ah[mi] = hh; al[mi] = ll;
            }
#pragma unroll
            for (int nj = 0; nj < 4; ++nj) {
                int r   = rB + nj * 16;
                int off = r * 128 + (((s * 4 + kq) ^ (r & 7)) * 16);
                bh[nj] = *(const h16x8*)(lds + 32768 + off);
                bl[nj] = *(const h16x8*)(lds + 49152 + off);
            }
#pragma unroll
            for (int mi = 0; mi < 4; ++mi)
#pragma unroll
                for (int nj = 0; nj < 4; ++nj) {
                    acc[mi][nj] = __builtin_amdgcn_mfma_f32_16x16x32_f16(ah[mi], bh[nj], acc[mi][nj], 0, 0, 0);
                    acc[mi][nj] = __builtin_amdgcn_mfma_f32_16x16x32_f16(ah[mi], bl[nj], acc[mi][nj], 0, 0, 0);
                    acc[mi][nj] = __builtin_amdgcn_mfma_f32_16x16x32_f16(al[mi], bh[nj], acc[mi][nj], 0, 0, 0);
                }
        }
    }

#pragma unroll
    for (int mi = 0; mi < 4; ++mi)
#pragma unroll
        for (int nj = 0; nj < 4; ++nj) {
            int n  = n0 + wc * 64 + nj * 16 + (lane & 15);
            int m0 = i0 + wr * 64 + mi * 16 + ((lane >> 4) * 4);
#pragma unroll
            for (int rg = 0; rg < 4; ++rg) {
                size_t off = ((size_t)b * LROWS + (m0 + rg)) * FDIM + n;
                float res = (float)Xh[off] + (float)Xl[off];
                float y   = res + acc[mi][nj][rg];
                y = y > 0.f ? y : 0.f;
                NodeOut[off] = y;
                h16 h_, l_; split2(y, h_, l_);
                Xh[off] = h_; Xl[off] = l_;
            }
        }
}

// ---------- final: split node_rep[2] into target/claim slots ----------
__global__ __launch_bounds__(256) void copy_final(const float* __restrict__ nr2,
                                                  float* __restrict__ out) {
    size_t i4 = (size_t)blockIdx.x * 256 + threadIdx.x;
    size_t e  = i4 * 4;
    int b  = (int)(e >> 18);
    int rf = (int)(e & 262143);
    int r  = rf >> 8, f = rf & 255;
    f32x4 v = *(const f32x4*)(nr2 + e);
    float* dst = (r < 256)
        ? out + OFF_TGT + ((size_t)b << 16) + ((size_t)r << 8) + f
        : out + OFF_CLM + (size_t)b * 196608 + ((size_t)(r - 256) << 8) + f;
    *(f32x4*)dst = v;
}

// ---------- host ----------
extern "C" void kernel_launch(void* const* d_in, const int* in_sizes, int n_in,
                              void* d_out, int out_size, void* d_ws, size_t ws_size,
                              hipStream_t stream) {
    (void)in_sizes; (void)n_in; (void)out_size; (void)ws_size;
    const float* tgt = (const float*)d_in[0];
    const float* clm = (const float*)d_in[1];
    // d_in[2] = batch_adj: unused by the reference computation
    const float* W   = (const float*)d_in[3];
    float* out = (float*)d_out;
    char*  ws  = (char*)d_ws;

    h16* xh = (h16*)(ws);
    h16* xl = (h16*)(ws + (8ull << 20));
    h16* th = (h16*)(ws + (16ull << 20));
    h16* tl = (h16*)(ws + (24ull << 20));
    h16* wh = (h16*)(ws + (32ull << 20));
    h16* wl = (h16*)(ws + (32ull << 20) + (1ull << 19));

    convert_x<<<4096, 256, 0, stream>>>(tgt, clm, xh, xl);
    convert_w<<<192, 256, 0, stream>>>(W, wh, wl);

    for (int L = 0; L < 3; ++L) {
        float* at = out + OFF_AT + (size_t)L * 16777216ull;
        float* nr = out + OFF_NR + (size_t)L * 4194304ull;
        gemm_split<0><<<dim3(8, 8, 16), 256, 0, stream>>>(xh, xl, xh, xl, at, nullptr, nullptr);
        softmax_rows<<<16384, 256, 0, stream>>>(at);
        gemm_split<1><<<dim3(2, 8, 16), 256, 0, stream>>>(xh, xl, wh + (size_t)L * 65536, wl + (size_t)L * 65536,
                                                          nullptr, th, tl);
        gemm_pv<<<dim3(2, 8, 16), 256, 0, stream>>>(at, th, tl, xh, xl, nr);
    }
    copy_final<<<4096, 256, 0, stream>>>(out + OFF_NR + 2ull * 4194304ull, out);
}

// Round 2
// 356.827 us; speedup vs baseline: 1.2175x; 1.2175x over previous
//
#include <hip/hip_runtime.h>

// ---------- types ----------
typedef _Float16 h16;
typedef _Float16 h16x8 __attribute__((ext_vector_type(8)));
typedef _Float16 h16x4 __attribute__((ext_vector_type(4)));
typedef float    f32x4 __attribute__((ext_vector_type(4)));
typedef unsigned int u32x4 __attribute__((ext_vector_type(4)));

#define NBATCH 16
#define LROWS  1024
#define FDIM   256

// d_out element offsets (fp32 elements)
#define OFF_TGT 0ull
#define OFF_CLM 1048576ull
#define OFF_NR  4194304ull     // + layer*4194304
#define OFF_AT  16777216ull    // + layer*16777216

__device__ __forceinline__ void split2(float x, h16& h, h16& l) {
    h = (h16)x;
    l = (h16)(x - (float)h);
}

// global_load_lds width-16 helper (dest = wave-uniform base + lane*16)
typedef const __attribute__((address_space(1))) void gvoid;
typedef __attribute__((address_space(3))) void lvoid;
__device__ __forceinline__ void gl_lds16(const void* g, void* l) {
    __builtin_amdgcn_global_load_lds((gvoid*)g, (lvoid*)l, 16, 0, 0);
}

// ---------- init: concat(target,claim) -> x hi/lo fp16 ----------
__global__ __launch_bounds__(256) void convert_x(const float* __restrict__ tgt,
                                                 const float* __restrict__ clm,
                                                 h16* __restrict__ xh, h16* __restrict__ xl) {
    size_t i4 = (size_t)blockIdx.x * 256 + threadIdx.x;
    size_t e  = i4 * 4;
    int b  = (int)(e >> 18);
    int rf = (int)(e & 262143);
    int r  = rf >> 8, f = rf & 255;
    const float* src = (r < 256)
        ? tgt + ((size_t)b << 16) + ((size_t)r << 8) + f
        : clm + (size_t)b * 196608 + ((size_t)(r - 256) << 8) + f;
    f32x4 v = *(const f32x4*)src;
    h16x4 hv, lv;
#pragma unroll
    for (int j = 0; j < 4; ++j) { h16 hh, ll; split2(v[j], hh, ll); hv[j] = hh; lv[j] = ll; }
    *(h16x4*)(xh + e) = hv;
    *(h16x4*)(xl + e) = lv;
}

__global__ __launch_bounds__(256) void convert_w(const float* __restrict__ W,
                                                 h16* __restrict__ wh, h16* __restrict__ wl) {
    size_t e = ((size_t)blockIdx.x * 256 + threadIdx.x) * 4;
    f32x4 v = *(const f32x4*)(W + e);
    h16x4 hv, lv;
#pragma unroll
    for (int j = 0; j < 4; ++j) { h16 hh, ll; split2(v[j], hh, ll); hv[j] = hh; lv[j] = ll; }
    *(h16x4*)(wh + e) = hv;
    *(h16x4*)(wl + e) = lv;
}

// ---------- corr: logits = x x^T (per batch), 3-term split-fp16 MFMA ----------
// Writes raw logits fp32 to d_out attn slot + per-(row,64col-chunk) (max,sumexp) partials.
__global__ __launch_bounds__(256, 2) void gemm_corr(
    const h16* __restrict__ Xh, const h16* __restrict__ Xl,
    float* __restrict__ At, float2* __restrict__ part) {
    const int b  = blockIdx.z;
    const int i0 = blockIdx.y * 128;
    const int j0 = blockIdx.x * 128;
    const int t  = threadIdx.x;
    const int lane = t & 63, wid = t >> 6;
    const int wr = wid >> 1, wc = wid & 1;

    __shared__ alignas(16) char lds[65536];  // Ah 0 | Al 16K | Bh 32K | Bl 48K, each [128][64]h16

    const size_t arow = ((size_t)b * LROWS + i0) * 256;
    const size_t brow = ((size_t)b * LROWS + j0) * 256;

    f32x4 acc[4][4];
#pragma unroll
    for (int i = 0; i < 4; ++i)
#pragma unroll
        for (int j = 0; j < 4; ++j) acc[i][j] = (f32x4){0.f, 0.f, 0.f, 0.f};

    const int grow = t >> 3;   // 0..31
    const int gq   = t & 7;

    for (int kt = 0; kt < 4; ++kt) {
        __syncthreads();       // prior MFMA done reading LDS
#pragma unroll
        for (int it = 0; it < 4; ++it) {
            int r = it * 32 + grow;
            size_t so = (size_t)r * 256 + kt * 64 + ((gq ^ (r & 7)) << 3);  // pre-swizzled source
            char* d = lds + it * 4096 + wid * 1024;                         // linear LDS dest
            gl_lds16(Xh + arow + so, d);
            gl_lds16(Xl + arow + so, d + 16384);
            gl_lds16(Xh + brow + so, d + 32768);
            gl_lds16(Xl + brow + so, d + 49152);
        }
        __syncthreads();       // drains global_load_lds

        const int kq = lane >> 4;
        const int rA = wr * 64 + (lane & 15);
        const int rB = wc * 64 + (lane & 15);
#pragma unroll
        for (int s = 0; s < 2; ++s) {
            h16x8 ah[4], al[4], bh[4], bl[4];
#pragma unroll
            for (int mi = 0; mi < 4; ++mi) {
                int r   = rA + mi * 16;
                int off = r * 128 + (((s * 4 + kq) ^ (r & 7)) * 16);
                ah[mi] = *(const h16x8*)(lds + off);
                al[mi] = *(const h16x8*)(lds + 16384 + off);
            }
#pragma unroll
            for (int nj = 0; nj < 4; ++nj) {
                int r   = rB + nj * 16;
                int off = r * 128 + (((s * 4 + kq) ^ (r & 7)) * 16);
                bh[nj] = *(const h16x8*)(lds + 32768 + off);
                bl[nj] = *(const h16x8*)(lds + 49152 + off);
            }
#pragma unroll
            for (int mi = 0; mi < 4; ++mi)
#pragma unroll
                for (int nj = 0; nj < 4; ++nj) {
                    acc[mi][nj] = __builtin_amdgcn_mfma_f32_16x16x32_f16(ah[mi], bh[nj], acc[mi][nj], 0, 0, 0);
                    acc[mi][nj] = __builtin_amdgcn_mfma_f32_16x16x32_f16(ah[mi], bl[nj], acc[mi][nj], 0, 0, 0);
                    acc[mi][nj] = __builtin_amdgcn_mfma_f32_16x16x32_f16(al[mi], bh[nj], acc[mi][nj], 0, 0, 0);
                }
        }
    }

    // store logits
    const int mBase = i0 + wr * 64;
    const int nBase = j0 + wc * 64;
    float* Cb = At + (size_t)b * LROWS * 1024;
#pragma unroll
    for (int mi = 0; mi < 4; ++mi)
#pragma unroll
        for (int nj = 0; nj < 4; ++nj) {
            int n  = nBase + nj * 16 + (lane & 15);
            int m0 = mBase + mi * 16 + ((lane >> 4) * 4);
#pragma unroll
            for (int rg = 0; rg < 4; ++rg)
                Cb[(size_t)(m0 + rg) * 1024 + n] = acc[mi][nj][rg];
        }

    // per-row tile partials over this wave's 64 cols
    const int chunk = blockIdx.x * 2 + wc;
#pragma unroll
    for (int mi = 0; mi < 4; ++mi)
#pragma unroll
        for (int rg = 0; rg < 4; ++rg) {
            float v0 = acc[mi][0][rg], v1 = acc[mi][1][rg];
            float v2 = acc[mi][2][rg], v3 = acc[mi][3][rg];
            float mx = fmaxf(fmaxf(v0, v1), fmaxf(v2, v3));
#pragma unroll
            for (int off = 8; off >= 1; off >>= 1) mx = fmaxf(mx, __shfl_xor(mx, off, 16));
            float s = __expf(v0 - mx) + __expf(v1 - mx) + __expf(v2 - mx) + __expf(v3 - mx);
#pragma unroll
            for (int off = 8; off >= 1; off >>= 1) s += __shfl_xor(s, off, 16);
            if ((lane & 15) == 0) {
                int row = mBase + mi * 16 + ((lane >> 4) * 4) + rg;
                part[((size_t)b * 1024 + row) * 16 + chunk] = make_float2(mx, s);
            }
        }
}

// ---------- reduce: 16 chunk partials -> per-row (M, 1/S) ----------
__global__ __launch_bounds__(256) void reduce_rows(const float2* __restrict__ part,
                                                   float2* __restrict__ stats) {
    int r = blockIdx.x * 256 + threadIdx.x;   // 16384 rows
    const float2* p = part + (size_t)r * 16;
    float2 v[16];
    float M = -3.0e38f;
#pragma unroll
    for (int c = 0; c < 16; ++c) { v[c] = p[c]; M = fmaxf(M, v[c].x); }
    float S = 0.f;
#pragma unroll
    for (int c = 0; c < 16; ++c) S += v[c].y * __expf(v[c].x - M);
    stats[r] = make_float2(M, 1.0f / S);
}

// ---------- trans: t = x · W^T  (K=256), store transposed hi/lo fp16 tT[b][g][l] ----------
__global__ __launch_bounds__(256, 2) void gemm_trans(
    const h16* __restrict__ Ah, const h16* __restrict__ Al,
    const h16* __restrict__ Bh, const h16* __restrict__ Bl,
    h16* __restrict__ Th, h16* __restrict__ Tl) {
    constexpr int K = 256;
    const int b  = blockIdx.z;
    const int i0 = blockIdx.y * 128;
    const int j0 = blockIdx.x * 128;
    const int t  = threadIdx.x;
    const int lane = t & 63, wid = t >> 6;
    const int wr = wid >> 1, wc = wid & 1;

    __shared__ alignas(16) char lds[65536];

    const size_t abase = ((size_t)b * LROWS + i0) * K;
    const size_t bbase = (size_t)j0 * K;

    f32x4 acc[4][4];
#pragma unroll
    for (int i = 0; i < 4; ++i)
#pragma unroll
        for (int j = 0; j < 4; ++j) acc[i][j] = (f32x4){0.f, 0.f, 0.f, 0.f};

    for (int kt = 0; kt < K / 64; ++kt) {
        const h16* aH = Ah + abase + kt * 64;
        const h16* aL = Al + abase + kt * 64;
        const h16* bH = Bh + bbase + kt * 64;
        const h16* bL = Bl + bbase + kt * 64;
        u32x4 vAh[4], vAl[4], vBh[4], vBl[4];
#pragma unroll
        for (int it = 0; it < 4; ++it) {
            int row = it * 32 + (t >> 3);
            int q   = t & 7;
            size_t go = (size_t)row * K + q * 8;
            vAh[it] = *(const u32x4*)(aH + go);
            vAl[it] = *(const u32x4*)(aL + go);
            vBh[it] = *(const u32x4*)(bH + go);
            vBl[it] = *(const u32x4*)(bL + go);
        }
        __syncthreads();
#pragma unroll
        for (int it = 0; it < 4; ++it) {
            int row = it * 32 + (t >> 3);
            int p   = (t & 7) ^ (row & 7);
            int off = row * 128 + p * 16;
            *(u32x4*)(lds + off)         = vAh[it];
            *(u32x4*)(lds + 16384 + off) = vAl[it];
            *(u32x4*)(lds + 32768 + off) = vBh[it];
            *(u32x4*)(lds + 49152 + off) = vBl[it];
        }
        __syncthreads();

        const int kq = lane >> 4;
        const int rA = wr * 64 + (lane & 15);
        const int rB = wc * 64 + (lane & 15);
#pragma unroll
        for (int s = 0; s < 2; ++s) {
            h16x8 ah[4], al[4], bh[4], bl[4];
#pragma unroll
            for (int mi = 0; mi < 4; ++mi) {
                int r   = rA + mi * 16;
                int off = r * 128 + (((s * 4 + kq) ^ (r & 7)) * 16);
                ah[mi] = *(const h16x8*)(lds + off);
                al[mi] = *(const h16x8*)(lds + 16384 + off);
            }
#pragma unroll
            for (int nj = 0; nj < 4; ++nj) {
                int r   = rB + nj * 16;
                int off = r * 128 + (((s * 4 + kq) ^ (r & 7)) * 16);
                bh[nj] = *(const h16x8*)(lds + 32768 + off);
                bl[nj] = *(const h16x8*)(lds + 49152 + off);
            }
#pragma unroll
            for (int mi = 0; mi < 4; ++mi)
#pragma unroll
                for (int nj = 0; nj < 4; ++nj) {
                    acc[mi][nj] = __builtin_amdgcn_mfma_f32_16x16x32_f16(ah[mi], bh[nj], acc[mi][nj], 0, 0, 0);
                    acc[mi][nj] = __builtin_amdgcn_mfma_f32_16x16x32_f16(ah[mi], bl[nj], acc[mi][nj], 0, 0, 0);
                    acc[mi][nj] = __builtin_amdgcn_mfma_f32_16x16x32_f16(al[mi], bh[nj], acc[mi][nj], 0, 0, 0);
                }
        }
    }

    const int mBase = i0 + wr * 64;
    const int nBase = j0 + wc * 64;
#pragma unroll
    for (int mi = 0; mi < 4; ++mi)
#pragma unroll
        for (int nj = 0; nj < 4; ++nj) {
            int n  = nBase + nj * 16 + (lane & 15);
            int m0 = mBase + mi * 16 + ((lane >> 4) * 4);
            h16x4 hv, lv;
#pragma unroll
            for (int rg = 0; rg < 4; ++rg) { h16 hh, ll; split2(acc[mi][nj][rg], hh, ll); hv[rg] = hh; lv[rg] = ll; }
            size_t off = ((size_t)b * 256 + n) * 1024 + m0;  // tT[b][g][l]
            *(h16x4*)(Th + off) = hv;
            *(h16x4*)(Tl + off) = lv;
        }
}

// ---------- PV fused: p = exp(l-M)/S in place; Node = relu(x + p·t) ----------
// M-tile 32, N full 256, K=1024, Kt=64. 512 blocks, 2/CU.
__global__ __launch_bounds__(256, 2) void gemm_pv(
    float* __restrict__ At,                        // logits in, normalized p out (in place)
    const h16* __restrict__ Th, const h16* __restrict__ Tl,
    const float2* __restrict__ stats,
    h16* __restrict__ Xh, h16* __restrict__ Xl,
    float* __restrict__ NodeOut, float* __restrict__ OutBase, int last) {
    const int id   = blockIdx.x;
    const int xcd  = id & 7, rest = id >> 3;
    const int b    = (xcd << 1) | (rest & 1);      // 2 batches per XCD -> t stays in L2
    const int mt   = rest >> 1;                    // 0..31
    const int i0   = mt * 32;
    const int t    = threadIdx.x;
    const int lane = t & 63, wid = t >> 6;
    const int wr   = wid >> 1, wc = wid & 1;

    __shared__ alignas(16) char lds[73728];
    // Ah [32][64]h16 @0 | Al @4096 | Bh [256][64]h16 @8192 | Bl @40960

    float* Arow = At + ((size_t)b * LROWS + i0) * 1024;
    const size_t tbase = (size_t)b * 256 * 1024;

    const int ar0 = t >> 4;      // staging row 0..15 (and +16)
    const int aq  = t & 15;
    float2 st0 = stats[(size_t)b * 1024 + i0 + ar0];
    float2 st1 = stats[(size_t)b * 1024 + i0 + 16 + ar0];

    f32x4 acc[8];
#pragma unroll
    for (int i = 0; i < 8; ++i) acc[i] = (f32x4){0.f, 0.f, 0.f, 0.f};

    const int bgrow = t >> 3;    // 0..31
    const int bq    = t & 7;

    for (int kt = 0; kt < 16; ++kt) {
        // A logits loads (global only — safe before barrier)
        f32x4 va0 = *(const f32x4*)(Arow + (size_t)ar0 * 1024 + kt * 64 + aq * 4);
        f32x4 va1 = *(const f32x4*)(Arow + (size_t)(16 + ar0) * 1024 + kt * 64 + aq * 4);
        __syncthreads();         // prior MFMA done reading LDS

        // B: async global->LDS with pre-swizzled per-lane source
#pragma unroll
        for (int it = 0; it < 8; ++it) {
            int g = it * 32 + bgrow;
            size_t so = tbase + (size_t)g * 1024 + kt * 64 + ((bq ^ (g & 7)) << 3);
            char* d = lds + 8192 + it * 4096 + wid * 1024;
            gl_lds16(Th + so, d);
            gl_lds16(Tl + so, d + 32768);
        }

        // p = exp(v - M) * invS; write back in place; stage A hi/lo to LDS
        f32x4 p0, p1;
#pragma unroll
        for (int e = 0; e < 4; ++e) p0[e] = __expf(va0[e] - st0.x) * st0.y;
#pragma unroll
        for (int e = 0; e < 4; ++e) p1[e] = __expf(va1[e] - st1.x) * st1.y;
        *(f32x4*)(Arow + (size_t)ar0 * 1024 + kt * 64 + aq * 4)        = p0;
        *(f32x4*)(Arow + (size_t)(16 + ar0) * 1024 + kt * 64 + aq * 4) = p1;
        h16x4 h0, l0, h1, l1;
#pragma unroll
        for (int e = 0; e < 4; ++e) { h16 hh, ll; split2(p0[e], hh, ll); h0[e] = hh; l0[e] = ll; }
#pragma unroll
        for (int e = 0; e < 4; ++e) { h16 hh, ll; split2(p1[e], hh, ll); h1[e] = hh; l1[e] = ll; }
        {
            int c = aq >> 1, hb = (aq & 1) * 8;
            int r1 = 16 + ar0;
            int o0 = ar0 * 128 + ((c ^ (ar0 & 7)) * 16) + hb;
            int o1 = r1 * 128 + ((c ^ (r1 & 7)) * 16) + hb;
            *(h16x4*)(lds + o0)        = h0;
            *(h16x4*)(lds + 4096 + o0) = l0;
            *(h16x4*)(lds + o1)        = h1;
            *(h16x4*)(lds + 4096 + o1) = l1;
        }
        __syncthreads();         // drains ds_writes + global_load_lds

        const int kq = lane >> 4;
        const int rA = wr * 16 + (lane & 15);
#pragma unroll
        for (int s = 0; s < 2; ++s) {
            int ca = ((s * 4 + kq) ^ (rA & 7)) * 16;
            h16x8 ah = *(const h16x8*)(lds + rA * 128 + ca);
            h16x8 al = *(const h16x8*)(lds + 4096 + rA * 128 + ca);
#pragma unroll
            for (int nf = 0; nf < 8; ++nf) {
                int g  = wc * 128 + nf * 16 + (lane & 15);
                int cb = ((s * 4 + kq) ^ (g & 7)) * 16;
                h16x8 bh = *(const h16x8*)(lds + 8192 + g * 128 + cb);
                h16x8 bl = *(const h16x8*)(lds + 40960 + g * 128 + cb);
                acc[nf] = __builtin_amdgcn_mfma_f32_16x16x32_f16(ah, bh, acc[nf], 0, 0, 0);
                acc[nf] = __builtin_amdgcn_mfma_f32_16x16x32_f16(ah, bl, acc[nf], 0, 0, 0);
                acc[nf] = __builtin_amdgcn_mfma_f32_16x16x32_f16(al, bh, acc[nf], 0, 0, 0);
            }
        }
    }

    // epilogue: residual + relu, update x hi/lo, write node (+final slices)
#pragma unroll
    for (int nf = 0; nf < 8; ++nf) {
        int n = wc * 128 + nf * 16 + (lane & 15);
#pragma unroll
        for (int rg = 0; rg < 4; ++rg) {
            int m = i0 + wr * 16 + ((lane >> 4) * 4) + rg;
            size_t off = ((size_t)b * LROWS + m) * FDIM + n;
            float res = (float)Xh[off] + (float)Xl[off];
            float y   = res + acc[nf][rg];
            y = y > 0.f ? y : 0.f;
            NodeOut[off] = y;
            h16 hh, ll; split2(y, hh, ll);
            Xh[off] = hh; Xl[off] = ll;
            if (last) {
                float* dst = (m < 256)
                    ? OutBase + OFF_TGT + ((size_t)b << 16) + ((size_t)m << 8) + n
                    : OutBase + OFF_CLM + (size_t)b * 196608 + ((size_t)(m - 256) << 8) + n;
                *dst = y;
            }
        }
    }
}

// ---------- host ----------
extern "C" void kernel_launch(void* const* d_in, const int* in_sizes, int n_in,
                              void* d_out, int out_size, void* d_ws, size_t ws_size,
                              hipStream_t stream) {
    (void)in_sizes; (void)n_in; (void)out_size; (void)ws_size;
    const float* tgt = (const float*)d_in[0];
    const float* clm = (const float*)d_in[1];
    // d_in[2] = batch_adj: unused by the reference computation
    const float* W   = (const float*)d_in[3];
    float* out = (float*)d_out;
    char*  ws  = (char*)d_ws;

    h16* xh = (h16*)(ws);
    h16* xl = (h16*)(ws + (8ull << 20));
    h16* th = (h16*)(ws + (16ull << 20));
    h16* tl = (h16*)(ws + (24ull << 20));
    h16* wh = (h16*)(ws + (32ull << 20));
    h16* wl = (h16*)(ws + (32ull << 20) + (512ull << 10));
    float2* part  = (float2*)(ws + (34ull << 20));   // 16384 rows * 16 chunks * 8B = 2 MB
    float2* stats = (float2*)(ws + (36ull << 20));   // 16384 * 8B

    convert_x<<<4096, 256, 0, stream>>>(tgt, clm, xh, xl);
    convert_w<<<192, 256, 0, stream>>>(W, wh, wl);

    for (int L = 0; L < 3; ++L) {
        float* at = out + OFF_AT + (size_t)L * 16777216ull;
        float* nr = out + OFF_NR + (size_t)L * 4194304ull;
        gemm_corr<<<dim3(8, 8, 16), 256, 0, stream>>>(xh, xl, at, part);
        reduce_rows<<<64, 256, 0, stream>>>(part, stats);
        gemm_trans<<<dim3(2, 8, 16), 256, 0, stream>>>(xh, xl,
                                                       wh + (size_t)L * 65536, wl + (size_t)L * 65536,
                                                       th, tl);
        gemm_pv<<<512, 256, 0, stream>>>(at, th, tl, stats, xh, xl, nr, out, L == 2);
    }
}

// Round 3
// 338.503 us; speedup vs baseline: 1.2834x; 1.0541x over previous
//
#include <hip/hip_runtime.h>

// ---------- types ----------
typedef _Float16 h16;
typedef _Float16 h16x8 __attribute__((ext_vector_type(8)));
typedef _Float16 h16x4 __attribute__((ext_vector_type(4)));
typedef float    f32x4 __attribute__((ext_vector_type(4)));
typedef unsigned int u32x4 __attribute__((ext_vector_type(4)));

#define NBATCH 16
#define LROWS  1024
#define FDIM   256

// d_out element offsets (fp32 elements)
#define OFF_TGT 0ull
#define OFF_CLM 1048576ull
#define OFF_NR  4194304ull     // + layer*4194304
#define OFF_AT  16777216ull    // + layer*16777216

__device__ __forceinline__ void split2(float x, h16& h, h16& l) {
    h = (h16)x;
    l = (h16)(x - (float)h);
}

// global_load_lds width-16 helper (dest = wave-uniform base + lane*16)
typedef const __attribute__((address_space(1))) void gvoid;
typedef __attribute__((address_space(3))) void lvoid;
__device__ __forceinline__ void gl_lds16(const void* g, void* l) {
    __builtin_amdgcn_global_load_lds((gvoid*)g, (lvoid*)l, 16, 0, 0);
}

// ---------- init: concat(target,claim) -> x hi/lo fp16 ; W -> hi/lo fp16 ----------
__global__ __launch_bounds__(256) void convert_all(const float* __restrict__ tgt,
                                                   const float* __restrict__ clm,
                                                   const float* __restrict__ W,
                                                   h16* __restrict__ xh, h16* __restrict__ xl,
                                                   h16* __restrict__ wh, h16* __restrict__ wl) {
    int bid = blockIdx.x;
    if (bid < 4096) {
        size_t e = ((size_t)bid * 256 + threadIdx.x) * 4;
        int b  = (int)(e >> 18);
        int rf = (int)(e & 262143);
        int r  = rf >> 8, f = rf & 255;
        const float* src = (r < 256)
            ? tgt + ((size_t)b << 16) + ((size_t)r << 8) + f
            : clm + (size_t)b * 196608 + ((size_t)(r - 256) << 8) + f;
        f32x4 v = *(const f32x4*)src;
        h16x4 hv, lv;
#pragma unroll
        for (int j = 0; j < 4; ++j) { h16 hh, ll; split2(v[j], hh, ll); hv[j] = hh; lv[j] = ll; }
        *(h16x4*)(xh + e) = hv;
        *(h16x4*)(xl + e) = lv;
    } else {
        size_t e = ((size_t)(bid - 4096) * 256 + threadIdx.x) * 4;
        f32x4 v = *(const f32x4*)(W + e);
        h16x4 hv, lv;
#pragma unroll
        for (int j = 0; j < 4; ++j) { h16 hh, ll; split2(v[j], hh, ll); hv[j] = hh; lv[j] = ll; }
        *(h16x4*)(wh + e) = hv;
        *(h16x4*)(wl + e) = lv;
    }
}

// ---------- fused corr+trans ----------
// blockIdx.x<8 : corr j-tile — logits = x·x^T -> At (raw) + per-(row,64col) (max,sumexp)
// blockIdx.x>=8: trans j-tile — t = x·W^T -> tT hi/lo fp16 (transposed)
// Both: 3-term split-fp16 MFMA, K=256.
__global__ __launch_bounds__(256, 2) void gemm_ct(
    const h16* __restrict__ Xh, const h16* __restrict__ Xl,
    const h16* __restrict__ Wh, const h16* __restrict__ Wl,
    float* __restrict__ At, float2* __restrict__ part,
    h16* __restrict__ Th, h16* __restrict__ Tl) {
    const int b  = blockIdx.z;
    const bool isCorr = blockIdx.x < 8;
    const int i0 = blockIdx.y * 128;
    const int j0 = (isCorr ? blockIdx.x : (blockIdx.x - 8)) * 128;
    const int t  = threadIdx.x;
    const int lane = t & 63, wid = t >> 6;
    const int wr = wid >> 1, wc = wid & 1;

    __shared__ alignas(16) char lds[65536];  // Ah 0 | Al 16K | Bh 32K | Bl 48K, each [128][64]h16

    const size_t arow = ((size_t)b * LROWS + i0) * 256;
    const h16* bHp; const h16* bLp; size_t brow;
    if (isCorr) { bHp = Xh; bLp = Xl; brow = ((size_t)b * LROWS + j0) * 256; }
    else        { bHp = Wh; bLp = Wl; brow = (size_t)j0 * 256; }

    f32x4 acc[4][4];
#pragma unroll
    for (int i = 0; i < 4; ++i)
#pragma unroll
        for (int j = 0; j < 4; ++j) acc[i][j] = (f32x4){0.f, 0.f, 0.f, 0.f};

    const int grow = t >> 3;   // 0..31
    const int gq   = t & 7;

    for (int kt = 0; kt < 4; ++kt) {
        __syncthreads();       // prior MFMA done reading LDS
#pragma unroll
        for (int it = 0; it < 4; ++it) {
            int r = it * 32 + grow;
            size_t so = (size_t)r * 256 + kt * 64 + ((gq ^ (r & 7)) << 3);  // pre-swizzled source
            char* d = lds + it * 4096 + wid * 1024;                         // linear LDS dest
            gl_lds16(Xh + arow + so, d);
            gl_lds16(Xl + arow + so, d + 16384);
            gl_lds16(bHp + brow + so, d + 32768);
            gl_lds16(bLp + brow + so, d + 49152);
        }
        __syncthreads();       // drains global_load_lds

        const int kq = lane >> 4;
        const int rA = wr * 64 + (lane & 15);
        const int rB = wc * 64 + (lane & 15);
#pragma unroll
        for (int s = 0; s < 2; ++s) {
            h16x8 ah[4], al[4], bh[4], bl[4];
#pragma unroll
            for (int mi = 0; mi < 4; ++mi) {
                int r   = rA + mi * 16;
                int off = r * 128 + (((s * 4 + kq) ^ (r & 7)) * 16);
                ah[mi] = *(const h16x8*)(lds + off);
                al[mi] = *(const h16x8*)(lds + 16384 + off);
            }
#pragma unroll
            for (int nj = 0; nj < 4; ++nj) {
                int r   = rB + nj * 16;
                int off = r * 128 + (((s * 4 + kq) ^ (r & 7)) * 16);
                bh[nj] = *(const h16x8*)(lds + 32768 + off);
                bl[nj] = *(const h16x8*)(lds + 49152 + off);
            }
#pragma unroll
            for (int mi = 0; mi < 4; ++mi)
#pragma unroll
                for (int nj = 0; nj < 4; ++nj) {
                    acc[mi][nj] = __builtin_amdgcn_mfma_f32_16x16x32_f16(ah[mi], bh[nj], acc[mi][nj], 0, 0, 0);
                    acc[mi][nj] = __builtin_amdgcn_mfma_f32_16x16x32_f16(ah[mi], bl[nj], acc[mi][nj], 0, 0, 0);
                    acc[mi][nj] = __builtin_amdgcn_mfma_f32_16x16x32_f16(al[mi], bh[nj], acc[mi][nj], 0, 0, 0);
                }
        }
    }

    const int mBase = i0 + wr * 64;
    const int nBase = j0 + wc * 64;
    if (isCorr) {
        // store logits
        float* Cb = At + (size_t)b * LROWS * 1024;
#pragma unroll
        for (int mi = 0; mi < 4; ++mi)
#pragma unroll
            for (int nj = 0; nj < 4; ++nj) {
                int n  = nBase + nj * 16 + (lane & 15);
                int m0 = mBase + mi * 16 + ((lane >> 4) * 4);
#pragma unroll
                for (int rg = 0; rg < 4; ++rg)
                    Cb[(size_t)(m0 + rg) * 1024 + n] = acc[mi][nj][rg];
            }
        // per-row (max,sumexp) over this wave's 64 cols
        const int chunk = blockIdx.x * 2 + wc;
#pragma unroll
        for (int mi = 0; mi < 4; ++mi)
#pragma unroll
            for (int rg = 0; rg < 4; ++rg) {
                float v0 = acc[mi][0][rg], v1 = acc[mi][1][rg];
                float v2 = acc[mi][2][rg], v3 = acc[mi][3][rg];
                float mx = fmaxf(fmaxf(v0, v1), fmaxf(v2, v3));
#pragma unroll
                for (int off = 8; off >= 1; off >>= 1) mx = fmaxf(mx, __shfl_xor(mx, off, 16));
                float s = __expf(v0 - mx) + __expf(v1 - mx) + __expf(v2 - mx) + __expf(v3 - mx);
#pragma unroll
                for (int off = 8; off >= 1; off >>= 1) s += __shfl_xor(s, off, 16);
                if ((lane & 15) == 0) {
                    int row = mBase + mi * 16 + ((lane >> 4) * 4) + rg;
                    part[((size_t)b * 1024 + row) * 16 + chunk] = make_float2(mx, s);
                }
            }
    } else {
        // store t transposed, split hi/lo
#pragma unroll
        for (int mi = 0; mi < 4; ++mi)
#pragma unroll
            for (int nj = 0; nj < 4; ++nj) {
                int n  = nBase + nj * 16 + (lane & 15);
                int m0 = mBase + mi * 16 + ((lane >> 4) * 4);
                h16x4 hv, lv;
#pragma unroll
                for (int rg = 0; rg < 4; ++rg) { h16 hh, ll; split2(acc[mi][nj][rg], hh, ll); hv[rg] = hh; lv[rg] = ll; }
                size_t off = ((size_t)b * 256 + n) * 1024 + m0;  // tT[b][g][l]
                *(h16x4*)(Th + off) = hv;
                *(h16x4*)(Tl + off) = lv;
            }
    }
}

// ---------- PV fused: stats reduce + p = exp(l-M)/S in place + Node = relu(x + p·t) ----------
// M-tile 32, N full 256, K=1024, Kt=64. 512 blocks, 2/CU.
// attn MFMA operand: plain fp16 (p in [0,1], rel err 2^-12); t stays split hi/lo.
__global__ __launch_bounds__(256, 2) void gemm_pv(
    float* __restrict__ At,                        // logits in, normalized p out (in place)
    const h16* __restrict__ Th, const h16* __restrict__ Tl,
    const float2* __restrict__ part,
    h16* __restrict__ Xh, h16* __restrict__ Xl,
    float* __restrict__ NodeOut, float* __restrict__ OutBase, int last) {
    const int id   = blockIdx.x;
    const int xcd  = id & 7, rest = id >> 3;
    const int b    = (xcd << 1) | (rest & 1);      // same-b blocks share HW XCD -> tT in L2
    const int mt   = rest >> 1;                    // 0..31
    const int i0   = mt * 32;
    const int t    = threadIdx.x;
    const int lane = t & 63, wid = t >> 6;
    const int wr   = wid >> 1, wc = wid & 1;

    __shared__ alignas(16) char lds[69632];
    // Ah [32][64]h16 @0 (4K) | Bh [256][64]h16 @4096 (32K) | Bl @36864 (32K)
    __shared__ float2 sst[32];

    // stats prologue: reduce this block's 32 rows' 16 chunk partials
    if (t < 32) {
        const float2* pp = part + ((size_t)b * 1024 + i0 + t) * 16;
        float2 v[16];
        float M = -3.0e38f;
#pragma unroll
        for (int c = 0; c < 16; ++c) { v[c] = pp[c]; M = fmaxf(M, v[c].x); }
        float S = 0.f;
#pragma unroll
        for (int c = 0; c < 16; ++c) S += v[c].y * __expf(v[c].x - M);
        sst[t] = make_float2(M, 1.0f / S);
    }
    __syncthreads();

    float* Arow = At + ((size_t)b * LROWS + i0) * 1024;
    const size_t tbase = (size_t)b * 256 * 1024;

    const int ar0 = t >> 4;      // staging row 0..15 (and +16)
    const int aq  = t & 15;
    float2 st0 = sst[ar0];
    float2 st1 = sst[16 + ar0];

    f32x4 acc[8];
#pragma unroll
    for (int i = 0; i < 8; ++i) acc[i] = (f32x4){0.f, 0.f, 0.f, 0.f};

    const int bgrow = t >> 3;    // 0..31
    const int bq    = t & 7;

    for (int kt = 0; kt < 16; ++kt) {
        // A logits loads (global only — safe before barrier)
        f32x4 va0 = *(const f32x4*)(Arow + (size_t)ar0 * 1024 + kt * 64 + aq * 4);
        f32x4 va1 = *(const f32x4*)(Arow + (size_t)(16 + ar0) * 1024 + kt * 64 + aq * 4);
        __syncthreads();         // prior MFMA done reading LDS

        // B: async global->LDS with pre-swizzled per-lane source
#pragma unroll
        for (int it = 0; it < 8; ++it) {
            int g = it * 32 + bgrow;
            size_t so = tbase + (size_t)g * 1024 + kt * 64 + ((bq ^ (g & 7)) << 3);
            char* d = lds + 4096 + it * 4096 + wid * 1024;
            gl_lds16(Th + so, d);
            gl_lds16(Tl + so, d + 32768);
        }

        // p = exp(v - M) * invS; write back in place; stage A fp16 to LDS
        f32x4 p0, p1;
#pragma unroll
        for (int e = 0; e < 4; ++e) p0[e] = __expf(va0[e] - st0.x) * st0.y;
#pragma unroll
        for (int e = 0; e < 4; ++e) p1[e] = __expf(va1[e] - st1.x) * st1.y;
        *(f32x4*)(Arow + (size_t)ar0 * 1024 + kt * 64 + aq * 4)        = p0;
        *(f32x4*)(Arow + (size_t)(16 + ar0) * 1024 + kt * 64 + aq * 4) = p1;
        h16x4 h0, h1;
#pragma unroll
        for (int e = 0; e < 4; ++e) { h0[e] = (h16)p0[e]; h1[e] = (h16)p1[e]; }
        {
            int c = aq >> 1, hb = (aq & 1) * 8;
            int r1 = 16 + ar0;
            int o0 = ar0 * 128 + ((c ^ (ar0 & 7)) * 16) + hb;
            int o1 = r1 * 128 + ((c ^ (r1 & 7)) * 16) + hb;
            *(h16x4*)(lds + o0) = h0;
            *(h16x4*)(lds + o1) = h1;
        }
        __syncthreads();         // drains ds_writes + global_load_lds

        const int kq = lane >> 4;
        const int rA = wr * 16 + (lane & 15);
#pragma unroll
        for (int s = 0; s < 2; ++s) {
            int ca = ((s * 4 + kq) ^ (rA & 7)) * 16;
            h16x8 ah = *(const h16x8*)(lds + rA * 128 + ca);
#pragma unroll
            for (int nf = 0; nf < 8; ++nf) {
                int g  = wc * 128 + nf * 16 + (lane & 15);
                int cb = ((s * 4 + kq) ^ (g & 7)) * 16;
                h16x8 bh = *(const h16x8*)(lds + 4096 + g * 128 + cb);
                h16x8 bl = *(const h16x8*)(lds + 36864 + g * 128 + cb);
                acc[nf] = __builtin_amdgcn_mfma_f32_16x16x32_f16(ah, bh, acc[nf], 0, 0, 0);
                acc[nf] = __builtin_amdgcn_mfma_f32_16x16x32_f16(ah, bl, acc[nf], 0, 0, 0);
            }
        }
    }

    // epilogue: residual + relu, update x hi/lo, write node (+final slices)
#pragma unroll
    for (int nf = 0; nf < 8; ++nf) {
        int n = wc * 128 + nf * 16 + (lane & 15);
#pragma unroll
        for (int rg = 0; rg < 4; ++rg) {
            int m = i0 + wr * 16 + ((lane >> 4) * 4) + rg;
            size_t off = ((size_t)b * LROWS + m) * FDIM + n;
            float res = (float)Xh[off] + (float)Xl[off];
            float y   = res + acc[nf][rg];
            y = y > 0.f ? y : 0.f;
            NodeOut[off] = y;
            h16 hh, ll; split2(y, hh, ll);
            Xh[off] = hh; Xl[off] = ll;
            if (last) {
                float* dst = (m < 256)
                    ? OutBase + OFF_TGT + ((size_t)b << 16) + ((size_t)m << 8) + n
                    : OutBase + OFF_CLM + (size_t)b * 196608 + ((size_t)(m - 256) << 8) + n;
                *dst = y;
            }
        }
    }
}

// ---------- host ----------
extern "C" void kernel_launch(void* const* d_in, const int* in_sizes, int n_in,
                              void* d_out, int out_size, void* d_ws, size_t ws_size,
                              hipStream_t stream) {
    (void)in_sizes; (void)n_in; (void)out_size; (void)ws_size;
    const float* tgt = (const float*)d_in[0];
    const float* clm = (const float*)d_in[1];
    // d_in[2] = batch_adj: unused by the reference computation
    const float* W   = (const float*)d_in[3];
    float* out = (float*)d_out;
    char*  ws  = (char*)d_ws;

    h16* xh = (h16*)(ws);
    h16* xl = (h16*)(ws + (8ull << 20));
    h16* th = (h16*)(ws + (16ull << 20));
    h16* tl = (h16*)(ws + (24ull << 20));
    h16* wh = (h16*)(ws + (32ull << 20));
    h16* wl = (h16*)(ws + (32ull << 20) + (512ull << 10));
    float2* part = (float2*)(ws + (34ull << 20));   // 16384 rows * 16 chunks * 8B = 2 MB

    convert_all<<<4288, 256, 0, stream>>>(tgt, clm, W, xh, xl, wh, wl);

    for (int L = 0; L < 3; ++L) {
        float* at = out + OFF_AT + (size_t)L * 16777216ull;
        float* nr = out + OFF_NR + (size_t)L * 4194304ull;
        gemm_ct<<<dim3(10, 8, 16), 256, 0, stream>>>(xh, xl,
                                                     wh + (size_t)L * 65536, wl + (size_t)L * 65536,
                                                     at, part, th, tl);
        gemm_pv<<<512, 256, 0, stream>>>(at, th, tl, part, xh, xl, nr, out, L == 2);
    }
}

// Round 4
// 308.517 us; speedup vs baseline: 1.4082x; 1.0972x over previous
//
#include <hip/hip_runtime.h>

// ---------- types ----------
typedef _Float16 h16;
typedef _Float16 h16x8 __attribute__((ext_vector_type(8)));
typedef _Float16 h16x4 __attribute__((ext_vector_type(4)));
typedef float    f32x4 __attribute__((ext_vector_type(4)));
typedef unsigned int u32x4 __attribute__((ext_vector_type(4)));

#define NBATCH 16
#define LROWS  1024
#define FDIM   256

// d_out element offsets (fp32 elements)
#define OFF_TGT 0ull
#define OFF_CLM 1048576ull
#define OFF_NR  4194304ull     // + layer*4194304
#define OFF_AT  16777216ull    // + layer*16777216

__device__ __forceinline__ void split2(float x, h16& h, h16& l) {
    h = (h16)x;
    l = (h16)(x - (float)h);
}

// global_load_lds width-16 helper (dest = wave-uniform base + lane*16)
typedef const __attribute__((address_space(1))) void gvoid;
typedef __attribute__((address_space(3))) void lvoid;
__device__ __forceinline__ void gl_lds16(const void* g, void* l) {
    __builtin_amdgcn_global_load_lds((gvoid*)g, (lvoid*)l, 16, 0, 0);
}

// upper-triangle tile enumeration (36 pairs, it <= jt, 8x8 tiles)
__device__ const unsigned char TRI_I[36] = {
    0,0,0,0,0,0,0,0, 1,1,1,1,1,1,1, 2,2,2,2,2,2, 3,3,3,3,3, 4,4,4,4, 5,5,5, 6,6, 7};
__device__ const unsigned char TRI_J[36] = {
    0,1,2,3,4,5,6,7, 1,2,3,4,5,6,7, 2,3,4,5,6,7, 3,4,5,6,7, 4,5,6,7, 5,6,7, 6,7, 7};

// ---------- init: concat(target,claim) -> x hi/lo fp16 ; W -> hi/lo fp16 ----------
__global__ __launch_bounds__(256) void convert_all(const float* __restrict__ tgt,
                                                   const float* __restrict__ clm,
                                                   const float* __restrict__ W,
                                                   h16* __restrict__ xh, h16* __restrict__ xl,
                                                   h16* __restrict__ wh, h16* __restrict__ wl) {
    int bid = blockIdx.x;
    if (bid < 4096) {
        size_t e = ((size_t)bid * 256 + threadIdx.x) * 4;
        int b  = (int)(e >> 18);
        int rf = (int)(e & 262143);
        int r  = rf >> 8, f = rf & 255;
        const float* src = (r < 256)
            ? tgt + ((size_t)b << 16) + ((size_t)r << 8) + f
            : clm + (size_t)b * 196608 + ((size_t)(r - 256) << 8) + f;
        f32x4 v = *(const f32x4*)src;
        h16x4 hv, lv;
#pragma unroll
        for (int j = 0; j < 4; ++j) { h16 hh, ll; split2(v[j], hh, ll); hv[j] = hh; lv[j] = ll; }
        *(h16x4*)(xh + e) = hv;
        *(h16x4*)(xl + e) = lv;
    } else {
        size_t e = ((size_t)(bid - 4096) * 256 + threadIdx.x) * 4;
        f32x4 v = *(const f32x4*)(W + e);
        h16x4 hv, lv;
#pragma unroll
        for (int j = 0; j < 4; ++j) { h16 hh, ll; split2(v[j], hh, ll); hv[j] = hh; lv[j] = ll; }
        *(h16x4*)(wh + e) = hv;
        *(h16x4*)(wl + e) = lv;
    }
}

// ---------- fused corr(symmetric)+trans ----------
// 52 units per batch: u<36 -> corr upper-tri tile (TRI_I[u],TRI_J[u]);
//                     u>=36 -> trans tile (it = v>>1, jw = v&1).
// corr: logits = x·x^T, write tile (+transposed tile if off-diag) to At raw,
//       plus per-(row,64col-chunk) (max,sumexp) partials for both orientations.
// trans: t = x·W^T (2-term split), store transposed hi/lo fp16 tT[b][g][l].
__global__ __launch_bounds__(256, 2) void gemm_ct(
    const h16* __restrict__ Xh, const h16* __restrict__ Xl,
    const h16* __restrict__ Wh, const h16* __restrict__ Wl,
    float* __restrict__ At, float2* __restrict__ part,
    h16* __restrict__ Th, h16* __restrict__ Tl) {
    const int b = blockIdx.x / 52;
    const int u = blockIdx.x % 52;
    const bool isCorr = u < 36;
    int it, jt;
    if (isCorr) { it = TRI_I[u]; jt = TRI_J[u]; }
    else        { int v = u - 36; it = v >> 1; jt = v & 1; }
    const int i0 = it * 128;
    const int j0 = jt * 128;
    const int t  = threadIdx.x;
    const int lane = t & 63, wid = t >> 6;
    const int wr = wid >> 1, wc = wid & 1;

    __shared__ alignas(16) char lds[65536];  // Ah 0 | Al 16K | Bh 32K | Bl 48K, each [128][64]h16

    const size_t arow = ((size_t)b * LROWS + i0) * 256;
    const h16* bHp; const h16* bLp; size_t brow;
    if (isCorr) { bHp = Xh; bLp = Xl; brow = ((size_t)b * LROWS + j0) * 256; }
    else        { bHp = Wh; bLp = Wl; brow = (size_t)j0 * 256; }

    f32x4 acc[4][4];
#pragma unroll
    for (int i = 0; i < 4; ++i)
#pragma unroll
        for (int j = 0; j < 4; ++j) acc[i][j] = (f32x4){0.f, 0.f, 0.f, 0.f};

    const int grow = t >> 3;   // 0..31
    const int gq   = t & 7;

    for (int kt = 0; kt < 4; ++kt) {
        __syncthreads();       // prior MFMA done reading LDS
#pragma unroll
        for (int itr = 0; itr < 4; ++itr) {
            int r = itr * 32 + grow;
            size_t so = (size_t)r * 256 + kt * 64 + ((gq ^ (r & 7)) << 3);  // pre-swizzled source
            char* d = lds + itr * 4096 + wid * 1024;                        // linear LDS dest
            gl_lds16(Xh + arow + so, d);
            gl_lds16(Xl + arow + so, d + 16384);
            gl_lds16(bHp + brow + so, d + 32768);
            gl_lds16(bLp + brow + so, d + 49152);
        }
        __syncthreads();       // drains global_load_lds

        const int kq = lane >> 4;
        const int rA = wr * 64 + (lane & 15);
        const int rB = wc * 64 + (lane & 15);
#pragma unroll
        for (int s = 0; s < 2; ++s) {
            h16x8 ah[4], al[4], bh[4], bl[4];
#pragma unroll
            for (int mi = 0; mi < 4; ++mi) {
                int r   = rA + mi * 16;
                int off = r * 128 + (((s * 4 + kq) ^ (r & 7)) * 16);
                ah[mi] = *(const h16x8*)(lds + off);
                al[mi] = *(const h16x8*)(lds + 16384 + off);
            }
#pragma unroll
            for (int nj = 0; nj < 4; ++nj) {
                int r   = rB + nj * 16;
                int off = r * 128 + (((s * 4 + kq) ^ (r & 7)) * 16);
                bh[nj] = *(const h16x8*)(lds + 32768 + off);
                bl[nj] = *(const h16x8*)(lds + 49152 + off);
            }
#pragma unroll
            for (int mi = 0; mi < 4; ++mi)
#pragma unroll
                for (int nj = 0; nj < 4; ++nj) {
                    acc[mi][nj] = __builtin_amdgcn_mfma_f32_16x16x32_f16(ah[mi], bh[nj], acc[mi][nj], 0, 0, 0);
                    acc[mi][nj] = __builtin_amdgcn_mfma_f32_16x16x32_f16(ah[mi], bl[nj], acc[mi][nj], 0, 0, 0);
                    if (isCorr)
                        acc[mi][nj] = __builtin_amdgcn_mfma_f32_16x16x32_f16(al[mi], bh[nj], acc[mi][nj], 0, 0, 0);
                }
        }
    }

    const int mBase = i0 + wr * 64;
    const int nBase = j0 + wc * 64;
    if (isCorr) {
        float* Cb = At + (size_t)b * LROWS * 1024;
        // normal tile write
#pragma unroll
        for (int mi = 0; mi < 4; ++mi)
#pragma unroll
            for (int nj = 0; nj < 4; ++nj) {
                int n  = nBase + nj * 16 + (lane & 15);
                int m0 = mBase + mi * 16 + ((lane >> 4) * 4);
#pragma unroll
                for (int rg = 0; rg < 4; ++rg)
                    Cb[(size_t)(m0 + rg) * 1024 + n] = acc[mi][nj][rg];
            }
        // normal row-stats: rows in i-range, chunk in j-range
        {
            const int chunk = jt * 2 + wc;
#pragma unroll
            for (int mi = 0; mi < 4; ++mi)
#pragma unroll
                for (int rg = 0; rg < 4; ++rg) {
                    float v0 = acc[mi][0][rg], v1 = acc[mi][1][rg];
                    float v2 = acc[mi][2][rg], v3 = acc[mi][3][rg];
                    float mx = fmaxf(fmaxf(v0, v1), fmaxf(v2, v3));
#pragma unroll
                    for (int off = 8; off >= 1; off >>= 1) mx = fmaxf(mx, __shfl_xor(mx, off, 64));
                    float s = __expf(v0 - mx) + __expf(v1 - mx) + __expf(v2 - mx) + __expf(v3 - mx);
#pragma unroll
                    for (int off = 8; off >= 1; off >>= 1) s += __shfl_xor(s, off, 64);
                    if ((lane & 15) == 0) {
                        int row = mBase + mi * 16 + ((lane >> 4) * 4) + rg;
                        part[((size_t)b * 1024 + row) * 16 + chunk] = make_float2(mx, s);
                    }
                }
        }
        if (it != jt) {
            // transposed tile write: At[n][m]
#pragma unroll
            for (int mi = 0; mi < 4; ++mi)
#pragma unroll
                for (int nj = 0; nj < 4; ++nj) {
                    int n  = nBase + nj * 16 + (lane & 15);
                    int m0 = mBase + mi * 16 + ((lane >> 4) * 4);
                    f32x4 vv = acc[mi][nj];
                    *(f32x4*)(Cb + (size_t)n * 1024 + m0) = vv;
                }
            // transposed stats: rows in j-range (n), chunk in i-range
            const int chunk = it * 2 + wr;
#pragma unroll
            for (int nj = 0; nj < 4; ++nj) {
                float mx = -3.0e38f;
#pragma unroll
                for (int mi = 0; mi < 4; ++mi)
#pragma unroll
                    for (int rg = 0; rg < 4; ++rg) mx = fmaxf(mx, acc[mi][nj][rg]);
                mx = fmaxf(mx, __shfl_xor(mx, 16, 64));
                mx = fmaxf(mx, __shfl_xor(mx, 32, 64));
                float s = 0.f;
#pragma unroll
                for (int mi = 0; mi < 4; ++mi)
#pragma unroll
                    for (int rg = 0; rg < 4; ++rg) s += __expf(acc[mi][nj][rg] - mx);
                s += __shfl_xor(s, 16, 64);
                s += __shfl_xor(s, 32, 64);
                if (lane < 16) {
                    int n = nBase + nj * 16 + lane;
                    part[((size_t)b * 1024 + n) * 16 + chunk] = make_float2(mx, s);
                }
            }
        }
    } else {
        // store t transposed, split hi/lo
#pragma unroll
        for (int mi = 0; mi < 4; ++mi)
#pragma unroll
            for (int nj = 0; nj < 4; ++nj) {
                int n  = nBase + nj * 16 + (lane & 15);
                int m0 = mBase + mi * 16 + ((lane >> 4) * 4);
                h16x4 hv, lv;
#pragma unroll
                for (int rg = 0; rg < 4; ++rg) { h16 hh, ll; split2(acc[mi][nj][rg], hh, ll); hv[rg] = hh; lv[rg] = ll; }
                size_t off = ((size_t)b * 256 + n) * 1024 + m0;  // tT[b][g][l]
                *(h16x4*)(Th + off) = hv;
                *(h16x4*)(Tl + off) = lv;
            }
    }
}

// ---------- PV fused: stats reduce + p = exp(l-M)/S in place + Node = relu(x + p·t) ----------
// M-tile 32, N full 256, K=1024, Kt=64. 512 blocks, 2/CU.
// attn MFMA operand: plain fp16 (p in [0,1], rel err 2^-12); t stays split hi/lo.
__global__ __launch_bounds__(256, 2) void gemm_pv(
    float* __restrict__ At,                        // logits in, normalized p out (in place)
    const h16* __restrict__ Th, const h16* __restrict__ Tl,
    const float2* __restrict__ part,
    h16* __restrict__ Xh, h16* __restrict__ Xl,
    float* __restrict__ NodeOut, float* __restrict__ OutBase, int last) {
    const int id   = blockIdx.x;
    const int xcd  = id & 7, rest = id >> 3;
    const int b    = (xcd << 1) | (rest & 1);      // same-b blocks share HW XCD -> tT in L2
    const int mt   = rest >> 1;                    // 0..31
    const int i0   = mt * 32;
    const int t    = threadIdx.x;
    const int lane = t & 63, wid = t >> 6;
    const int wr   = wid >> 1, wc = wid & 1;

    __shared__ alignas(16) char lds[69632];
    // Ah [32][64]h16 @0 (4K) | Bh [256][64]h16 @4096 (32K) | Bl @36864 (32K)
    __shared__ float2 sst[32];

    // stats prologue: reduce this block's 32 rows' 16 chunk partials
    if (t < 32) {
        const float2* pp = part + ((size_t)b * 1024 + i0 + t) * 16;
        float2 v[16];
        float M = -3.0e38f;
#pragma unroll
        for (int c = 0; c < 16; ++c) { v[c] = pp[c]; M = fmaxf(M, v[c].x); }
        float S = 0.f;
#pragma unroll
        for (int c = 0; c < 16; ++c) S += v[c].y * __expf(v[c].x - M);
        sst[t] = make_float2(M, 1.0f / S);
    }
    __syncthreads();

    float* Arow = At + ((size_t)b * LROWS + i0) * 1024;
    const size_t tbase = (size_t)b * 256 * 1024;

    const int ar0 = t >> 4;      // staging row 0..15 (and +16)
    const int aq  = t & 15;
    float2 st0 = sst[ar0];
    float2 st1 = sst[16 + ar0];

    f32x4 acc[8];
#pragma unroll
    for (int i = 0; i < 8; ++i) acc[i] = (f32x4){0.f, 0.f, 0.f, 0.f};

    const int bgrow = t >> 3;    // 0..31
    const int bq    = t & 7;

    for (int kt = 0; kt < 16; ++kt) {
        // A logits loads (global only — safe before barrier)
        f32x4 va0 = *(const f32x4*)(Arow + (size_t)ar0 * 1024 + kt * 64 + aq * 4);
        f32x4 va1 = *(const f32x4*)(Arow + (size_t)(16 + ar0) * 1024 + kt * 64 + aq * 4);
        __syncthreads();         // prior MFMA done reading LDS

        // B: async global->LDS with pre-swizzled per-lane source
#pragma unroll
        for (int itr = 0; itr < 8; ++itr) {
            int g = itr * 32 + bgrow;
            size_t so = tbase + (size_t)g * 1024 + kt * 64 + ((bq ^ (g & 7)) << 3);
            char* d = lds + 4096 + itr * 4096 + wid * 1024;
            gl_lds16(Th + so, d);
            gl_lds16(Tl + so, d + 32768);
        }

        // p = exp(v - M) * invS; write back in place; stage A fp16 to LDS
        f32x4 p0, p1;
#pragma unroll
        for (int e = 0; e < 4; ++e) p0[e] = __expf(va0[e] - st0.x) * st0.y;
#pragma unroll
        for (int e = 0; e < 4; ++e) p1[e] = __expf(va1[e] - st1.x) * st1.y;
        *(f32x4*)(Arow + (size_t)ar0 * 1024 + kt * 64 + aq * 4)        = p0;
        *(f32x4*)(Arow + (size_t)(16 + ar0) * 1024 + kt * 64 + aq * 4) = p1;
        h16x4 h0, h1;
#pragma unroll
        for (int e = 0; e < 4; ++e) { h0[e] = (h16)p0[e]; h1[e] = (h16)p1[e]; }
        {
            int c = aq >> 1, hb = (aq & 1) * 8;
            int r1 = 16 + ar0;
            int o0 = ar0 * 128 + ((c ^ (ar0 & 7)) * 16) + hb;
            int o1 = r1 * 128 + ((c ^ (r1 & 7)) * 16) + hb;
            *(h16x4*)(lds + o0) = h0;
            *(h16x4*)(lds + o1) = h1;
        }
        __syncthreads();         // drains ds_writes + global_load_lds

        const int kq = lane >> 4;
        const int rA = wr * 16 + (lane & 15);
#pragma unroll
        for (int s = 0; s < 2; ++s) {
            int ca = ((s * 4 + kq) ^ (rA & 7)) * 16;
            h16x8 ah = *(const h16x8*)(lds + rA * 128 + ca);
#pragma unroll
            for (int nf = 0; nf < 8; ++nf) {
                int g  = wc * 128 + nf * 16 + (lane & 15);
                int cb = ((s * 4 + kq) ^ (g & 7)) * 16;
                h16x8 bh = *(const h16x8*)(lds + 4096 + g * 128 + cb);
                h16x8 bl = *(const h16x8*)(lds + 36864 + g * 128 + cb);
                acc[nf] = __builtin_amdgcn_mfma_f32_16x16x32_f16(ah, bh, acc[nf], 0, 0, 0);
                acc[nf] = __builtin_amdgcn_mfma_f32_16x16x32_f16(ah, bl, acc[nf], 0, 0, 0);
            }
        }
    }

    // epilogue: residual + relu, update x hi/lo, write node (+final slices)
#pragma unroll
    for (int nf = 0; nf < 8; ++nf) {
        int n = wc * 128 + nf * 16 + (lane & 15);
#pragma unroll
        for (int rg = 0; rg < 4; ++rg) {
            int m = i0 + wr * 16 + ((lane >> 4) * 4) + rg;
            size_t off = ((size_t)b * LROWS + m) * FDIM + n;
            float res = (float)Xh[off] + (float)Xl[off];
            float y   = res + acc[nf][rg];
            y = y > 0.f ? y : 0.f;
            NodeOut[off] = y;
            h16 hh, ll; split2(y, hh, ll);
            Xh[off] = hh; Xl[off] = ll;
            if (last) {
                float* dst = (m < 256)
                    ? OutBase + OFF_TGT + ((size_t)b << 16) + ((size_t)m << 8) + n
                    : OutBase + OFF_CLM + (size_t)b * 196608 + ((size_t)(m - 256) << 8) + n;
                *dst = y;
            }
        }
    }
}

// ---------- host ----------
extern "C" void kernel_launch(void* const* d_in, const int* in_sizes, int n_in,
                              void* d_out, int out_size, void* d_ws, size_t ws_size,
                              hipStream_t stream) {
    (void)in_sizes; (void)n_in; (void)out_size; (void)ws_size;
    const float* tgt = (const float*)d_in[0];
    const float* clm = (const float*)d_in[1];
    // d_in[2] = batch_adj: unused by the reference computation
    const float* W   = (const float*)d_in[3];
    float* out = (float*)d_out;
    char*  ws  = (char*)d_ws;

    h16* xh = (h16*)(ws);
    h16* xl = (h16*)(ws + (8ull << 20));
    h16* th = (h16*)(ws + (16ull << 20));
    h16* tl = (h16*)(ws + (24ull << 20));
    h16* wh = (h16*)(ws + (32ull << 20));
    h16* wl = (h16*)(ws + (32ull << 20) + (512ull << 10));
    float2* part = (float2*)(ws + (34ull << 20));   // 16384 rows * 16 chunks * 8B = 2 MB

    convert_all<<<4288, 256, 0, stream>>>(tgt, clm, W, xh, xl, wh, wl);

    for (int L = 0; L < 3; ++L) {
        float* at = out + OFF_AT + (size_t)L * 16777216ull;
        float* nr = out + OFF_NR + (size_t)L * 4194304ull;
        gemm_ct<<<832, 256, 0, stream>>>(xh, xl,
                                         wh + (size_t)L * 65536, wl + (size_t)L * 65536,
                                         at, part, th, tl);
        gemm_pv<<<512, 256, 0, stream>>>(at, th, tl, part, xh, xl, nr, out, L == 2);
    }
}

// Round 5
// 305.963 us; speedup vs baseline: 1.4199x; 1.0083x over previous
//
#include <hip/hip_runtime.h>

// ---------- types ----------
typedef _Float16 h16;
typedef _Float16 h16x8 __attribute__((ext_vector_type(8)));
typedef _Float16 h16x4 __attribute__((ext_vector_type(4)));
typedef float    f32x4 __attribute__((ext_vector_type(4)));

#define NBATCH 16
#define LROWS  1024
#define FDIM   256

// d_out element offsets (fp32 elements)
#define OFF_TGT 0ull
#define OFF_CLM 1048576ull
#define OFF_NR  4194304ull     // + layer*4194304
#define OFF_AT  16777216ull    // + layer*16777216

__device__ __forceinline__ void split2(float x, h16& h, h16& l) {
    h = (h16)x;
    l = (h16)(x - (float)h);
}

// global_load_lds width-16 helper (dest = wave-uniform base + lane*16)
typedef const __attribute__((address_space(1))) void gvoid;
typedef __attribute__((address_space(3))) void lvoid;
__device__ __forceinline__ void gl_lds16(const void* g, void* l) {
    __builtin_amdgcn_global_load_lds((gvoid*)g, (lvoid*)l, 16, 0, 0);
}

// upper-triangle tile enumeration (36 pairs, it <= jt, 8x8 tiles)
__device__ const unsigned char TRI_I[36] = {
    0,0,0,0,0,0,0,0, 1,1,1,1,1,1,1, 2,2,2,2,2,2, 3,3,3,3,3, 4,4,4,4, 5,5,5, 6,6, 7};
__device__ const unsigned char TRI_J[36] = {
    0,1,2,3,4,5,6,7, 1,2,3,4,5,6,7, 2,3,4,5,6,7, 3,4,5,6,7, 4,5,6,7, 5,6,7, 6,7, 7};

// ---------- init: concat(target,claim) -> x hi/lo fp16 ; W -> hi fp16 ----------
__global__ __launch_bounds__(256) void convert_all(const float* __restrict__ tgt,
                                                   const float* __restrict__ clm,
                                                   const float* __restrict__ W,
                                                   h16* __restrict__ xh, h16* __restrict__ xl,
                                                   h16* __restrict__ wh) {
    int bid = blockIdx.x;
    if (bid < 4096) {
        size_t e = ((size_t)bid * 256 + threadIdx.x) * 4;
        int b  = (int)(e >> 18);
        int rf = (int)(e & 262143);
        int r  = rf >> 8, f = rf & 255;
        const float* src = (r < 256)
            ? tgt + ((size_t)b << 16) + ((size_t)r << 8) + f
            : clm + (size_t)b * 196608 + ((size_t)(r - 256) << 8) + f;
        f32x4 v = *(const f32x4*)src;
        h16x4 hv, lv;
#pragma unroll
        for (int j = 0; j < 4; ++j) { h16 hh, ll; split2(v[j], hh, ll); hv[j] = hh; lv[j] = ll; }
        *(h16x4*)(xh + e) = hv;
        *(h16x4*)(xl + e) = lv;
    } else {
        size_t e = ((size_t)(bid - 4096) * 256 + threadIdx.x) * 4;
        f32x4 v = *(const f32x4*)(W + e);
        h16x4 hv;
#pragma unroll
        for (int j = 0; j < 4; ++j) hv[j] = (h16)v[j];
        *(h16x4*)(wh + e) = hv;
    }
}

// ---------- fused corr(symmetric)+trans, BK=32, 32KB LDS, 3+/CU ----------
// 52 units per batch: u<36 -> corr upper-tri tile (TRI_I,TRI_J); u>=36 -> trans tile.
// corr: 3-term split (ah·bh + ah·bl + al·bh); writes raw logits tile (+transpose
//       if off-diag) + per-(row,64col) (max,sumexp) partials for both orientations.
// trans: 2-term (ah+al)·Wh; store transposed fp16 tT[b][g][l].
__global__ __launch_bounds__(256, 3) void gemm_ct(
    const h16* __restrict__ Xh, const h16* __restrict__ Xl,
    const h16* __restrict__ Wh,
    float* __restrict__ At, float2* __restrict__ part,
    h16* __restrict__ Th) {
    const int b = blockIdx.x / 52;
    const int u = blockIdx.x % 52;
    const bool isCorr = u < 36;
    int it, jt;
    if (isCorr) { it = TRI_I[u]; jt = TRI_J[u]; }
    else        { int v = u - 36; it = v >> 1; jt = v & 1; }
    const int i0 = it * 128;
    const int j0 = jt * 128;
    const int t  = threadIdx.x;
    const int lane = t & 63, wid = t >> 6;
    const int wr = wid >> 1, wc = wid & 1;

    __shared__ alignas(16) char lds[32768];  // Ah@0 | Al@8K | Bh@16K | Bl@24K, each [128][32]h16

    const size_t arow = ((size_t)b * LROWS + i0) * 256;
    const h16* bHp; const h16* bLp; size_t brow;
    if (isCorr) { bHp = Xh; bLp = Xl; brow = ((size_t)b * LROWS + j0) * 256; }
    else        { bHp = Wh; bLp = Xl; brow = (size_t)j0 * 256; }   // bLp unused for trans

    f32x4 acc[4][4];
#pragma unroll
    for (int i = 0; i < 4; ++i)
#pragma unroll
        for (int j = 0; j < 4; ++j) acc[i][j] = (f32x4){0.f, 0.f, 0.f, 0.f};

    const int grow = t >> 2;   // 0..63 (row within 64-row staging pass)
    const int gq   = t & 3;    // 16B chunk 0..3 within 64B row

    for (int kt = 0; kt < 8; ++kt) {
        __syncthreads();       // prior MFMA done reading LDS
#pragma unroll
        for (int p = 0; p < 2; ++p) {
            int r = p * 64 + grow;
            // pre-swizzled source chunk (involution c ^ ((r>>1)&3)), linear LDS dest
            size_t so = (size_t)r * 256 + kt * 32 + ((gq ^ ((r >> 1) & 3)) << 3);
            char* d = lds + p * 4096 + wid * 1024;
            gl_lds16(Xh + arow + so, d);
            gl_lds16(Xl + arow + so, d + 8192);
            gl_lds16(bHp + brow + so, d + 16384);
            if (isCorr) gl_lds16(bLp + brow + so, d + 24576);
        }
        __syncthreads();       // drains global_load_lds

        const int kq = lane >> 4;                 // global k-chunk 0..3
        const int rA = wr * 64 + (lane & 15);
        const int rB = wc * 64 + (lane & 15);
        h16x8 ah[4], al[4], bh[4], bl[4];
#pragma unroll
        for (int mi = 0; mi < 4; ++mi) {
            int r   = rA + mi * 16;
            int off = r * 64 + ((kq ^ ((r >> 1) & 3)) << 4);
            ah[mi] = *(const h16x8*)(lds + off);
            al[mi] = *(const h16x8*)(lds + 8192 + off);
        }
#pragma unroll
        for (int nj = 0; nj < 4; ++nj) {
            int r   = rB + nj * 16;
            int off = r * 64 + ((kq ^ ((r >> 1) & 3)) << 4);
            bh[nj] = *(const h16x8*)(lds + 16384 + off);
            if (isCorr) bl[nj] = *(const h16x8*)(lds + 24576 + off);
        }
#pragma unroll
        for (int mi = 0; mi < 4; ++mi)
#pragma unroll
            for (int nj = 0; nj < 4; ++nj) {
                acc[mi][nj] = __builtin_amdgcn_mfma_f32_16x16x32_f16(ah[mi], bh[nj], acc[mi][nj], 0, 0, 0);
                acc[mi][nj] = __builtin_amdgcn_mfma_f32_16x16x32_f16(al[mi], bh[nj], acc[mi][nj], 0, 0, 0);
                if (isCorr)
                    acc[mi][nj] = __builtin_amdgcn_mfma_f32_16x16x32_f16(ah[mi], bl[nj], acc[mi][nj], 0, 0, 0);
            }
    }

    const int mBase = i0 + wr * 64;
    const int nBase = j0 + wc * 64;
    if (isCorr) {
        float* Cb = At + (size_t)b * LROWS * 1024;
        // normal tile write
#pragma unroll
        for (int mi = 0; mi < 4; ++mi)
#pragma unroll
            for (int nj = 0; nj < 4; ++nj) {
                int n  = nBase + nj * 16 + (lane & 15);
                int m0 = mBase + mi * 16 + ((lane >> 4) * 4);
#pragma unroll
                for (int rg = 0; rg < 4; ++rg)
                    Cb[(size_t)(m0 + rg) * 1024 + n] = acc[mi][nj][rg];
            }
        // normal row-stats: rows in i-range, chunk in j-range
        {
            const int chunk = jt * 2 + wc;
#pragma unroll
            for (int mi = 0; mi < 4; ++mi)
#pragma unroll
                for (int rg = 0; rg < 4; ++rg) {
                    float v0 = acc[mi][0][rg], v1 = acc[mi][1][rg];
                    float v2 = acc[mi][2][rg], v3 = acc[mi][3][rg];
                    float mx = fmaxf(fmaxf(v0, v1), fmaxf(v2, v3));
#pragma unroll
                    for (int off = 8; off >= 1; off >>= 1) mx = fmaxf(mx, __shfl_xor(mx, off, 64));
                    float s = __expf(v0 - mx) + __expf(v1 - mx) + __expf(v2 - mx) + __expf(v3 - mx);
#pragma unroll
                    for (int off = 8; off >= 1; off >>= 1) s += __shfl_xor(s, off, 64);
                    if ((lane & 15) == 0) {
                        int row = mBase + mi * 16 + ((lane >> 4) * 4) + rg;
                        part[((size_t)b * 1024 + row) * 16 + chunk] = make_float2(mx, s);
                    }
                }
        }
        if (it != jt) {
            // transposed tile write: At[n][m]
#pragma unroll
            for (int mi = 0; mi < 4; ++mi)
#pragma unroll
                for (int nj = 0; nj < 4; ++nj) {
                    int n  = nBase + nj * 16 + (lane & 15);
                    int m0 = mBase + mi * 16 + ((lane >> 4) * 4);
                    f32x4 vv = acc[mi][nj];
                    *(f32x4*)(Cb + (size_t)n * 1024 + m0) = vv;
                }
            // transposed stats: rows in j-range (n), chunk in i-range
            const int chunk = it * 2 + wr;
#pragma unroll
            for (int nj = 0; nj < 4; ++nj) {
                float mx = -3.0e38f;
#pragma unroll
                for (int mi = 0; mi < 4; ++mi)
#pragma unroll
                    for (int rg = 0; rg < 4; ++rg) mx = fmaxf(mx, acc[mi][nj][rg]);
                mx = fmaxf(mx, __shfl_xor(mx, 16, 64));
                mx = fmaxf(mx, __shfl_xor(mx, 32, 64));
                float s = 0.f;
#pragma unroll
                for (int mi = 0; mi < 4; ++mi)
#pragma unroll
                    for (int rg = 0; rg < 4; ++rg) s += __expf(acc[mi][nj][rg] - mx);
                s += __shfl_xor(s, 16, 64);
                s += __shfl_xor(s, 32, 64);
                if (lane < 16) {
                    int n = nBase + nj * 16 + lane;
                    part[((size_t)b * 1024 + n) * 16 + chunk] = make_float2(mx, s);
                }
            }
        }
    } else {
        // store t transposed, plain fp16
#pragma unroll
        for (int mi = 0; mi < 4; ++mi)
#pragma unroll
            for (int nj = 0; nj < 4; ++nj) {
                int n  = nBase + nj * 16 + (lane & 15);
                int m0 = mBase + mi * 16 + ((lane >> 4) * 4);
                h16x4 hv;
#pragma unroll
                for (int rg = 0; rg < 4; ++rg) hv[rg] = (h16)acc[mi][nj][rg];
                size_t off = ((size_t)b * 256 + n) * 1024 + m0;  // tT[b][g][l]
                *(h16x4*)(Th + off) = hv;
            }
    }
}

// ---------- PV fused: stats reduce + p = exp(l-M)/S in place + Node = relu(x + p·t) ----------
// M-tile 16, N full 256 (4 waves x 64-col quadrants), K=1024, Kt=64. 1024 blocks, 4/CU.
__global__ __launch_bounds__(256, 4) void gemm_pv(
    float* __restrict__ At,                        // logits in, normalized p out (in place)
    const h16* __restrict__ Th,
    const float2* __restrict__ part,
    h16* __restrict__ Xh, h16* __restrict__ Xl,
    float* __restrict__ NodeOut, float* __restrict__ OutBase, int last) {
    const int id   = blockIdx.x;
    const int xcd  = id & 7, rest = id >> 3;       // 1024 blocks
    const int b    = (xcd << 1) | (rest & 1);      // same-b blocks share HW XCD -> tT in L2
    const int mt   = rest >> 1;                    // 0..63
    const int i0   = mt * 16;
    const int t    = threadIdx.x;
    const int lane = t & 63, wid = t >> 6;
    const int wc   = wid;                          // n-quadrant 0..3

    __shared__ alignas(16) char lds[34816];
    // A [16][64]h16 @0 (2K, swizzled) | B [256][64]h16 @2048 (32K)
    __shared__ float2 sst[16];

    // stats prologue: reduce this block's 16 rows' 16 chunk partials
    if (t < 16) {
        const float2* pp = part + ((size_t)b * 1024 + i0 + t) * 16;
        float2 v[16];
        float M = -3.0e38f;
#pragma unroll
        for (int c = 0; c < 16; ++c) { v[c] = pp[c]; M = fmaxf(M, v[c].x); }
        float S = 0.f;
#pragma unroll
        for (int c = 0; c < 16; ++c) S += v[c].y * __expf(v[c].x - M);
        sst[t] = make_float2(M, 1.0f / S);
    }
    __syncthreads();

    float* Arow = At + ((size_t)b * LROWS + i0) * 1024;
    const size_t tbase = (size_t)b * 256 * 1024;

    const int ar0 = t >> 4;      // staging row 0..15
    const int aq  = t & 15;
    float2 st0 = sst[ar0];

    f32x4 acc[4];
#pragma unroll
    for (int i = 0; i < 4; ++i) acc[i] = (f32x4){0.f, 0.f, 0.f, 0.f};

    const int bgrow = t >> 3;    // 0..31
    const int bq    = t & 7;

    for (int kt = 0; kt < 16; ++kt) {
        // A logits load (global only — safe before barrier)
        f32x4 va0 = *(const f32x4*)(Arow + (size_t)ar0 * 1024 + kt * 64 + aq * 4);
        __syncthreads();         // prior MFMA done reading LDS

        // B: async global->LDS, pre-swizzled per-lane source, linear dest
#pragma unroll
        for (int itr = 0; itr < 8; ++itr) {
            int g = itr * 32 + bgrow;
            size_t so = tbase + (size_t)g * 1024 + kt * 64 + ((bq ^ (g & 7)) << 3);
            char* d = lds + 2048 + itr * 4096 + wid * 1024;
            gl_lds16(Th + so, d);
        }

        // p = exp(v - M) * invS; write back in place; stage A fp16 to LDS (swizzled write)
        f32x4 p0;
#pragma unroll
        for (int e = 0; e < 4; ++e) p0[e] = __expf(va0[e] - st0.x) * st0.y;
        *(f32x4*)(Arow + (size_t)ar0 * 1024 + kt * 64 + aq * 4) = p0;
        h16x4 h0;
#pragma unroll
        for (int e = 0; e < 4; ++e) h0[e] = (h16)p0[e];
        {
            int c = aq >> 1, hb = (aq & 1) * 8;
            int o0 = ar0 * 128 + ((c ^ (ar0 & 7)) * 16) + hb;
            *(h16x4*)(lds + o0) = h0;
        }
        __syncthreads();         // drains ds_writes + global_load_lds

        const int kq = lane >> 4;
        const int rA = lane & 15;
#pragma unroll
        for (int s = 0; s < 2; ++s) {
            int ca = ((s * 4 + kq) ^ (rA & 7)) * 16;
            h16x8 ah = *(const h16x8*)(lds + rA * 128 + ca);
#pragma unroll
            for (int nf = 0; nf < 4; ++nf) {
                int g  = wc * 64 + nf * 16 + (lane & 15);
                int cb = ((s * 4 + kq) ^ (g & 7)) * 16;
                h16x8 bh = *(const h16x8*)(lds + 2048 + g * 128 + cb);
                acc[nf] = __builtin_amdgcn_mfma_f32_16x16x32_f16(ah, bh, acc[nf], 0, 0, 0);
            }
        }
    }

    // epilogue: residual + relu, update x hi/lo, write node (+final slices)
#pragma unroll
    for (int nf = 0; nf < 4; ++nf) {
        int n = wc * 64 + nf * 16 + (lane & 15);
#pragma unroll
        for (int rg = 0; rg < 4; ++rg) {
            int m = i0 + ((lane >> 4) * 4) + rg;
            size_t off = ((size_t)b * LROWS + m) * FDIM + n;
            float res = (float)Xh[off] + (float)Xl[off];
            float y   = res + acc[nf][rg];
            y = y > 0.f ? y : 0.f;
            NodeOut[off] = y;
            h16 hh, ll; split2(y, hh, ll);
            Xh[off] = hh; Xl[off] = ll;
            if (last) {
                float* dst = (m < 256)
                    ? OutBase + OFF_TGT + ((size_t)b << 16) + ((size_t)m << 8) + n
                    : OutBase + OFF_CLM + (size_t)b * 196608 + ((size_t)(m - 256) << 8) + n;
                *dst = y;
            }
        }
    }
}

// ---------- host ----------
extern "C" void kernel_launch(void* const* d_in, const int* in_sizes, int n_in,
                              void* d_out, int out_size, void* d_ws, size_t ws_size,
                              hipStream_t stream) {
    (void)in_sizes; (void)n_in; (void)out_size; (void)ws_size;
    const float* tgt = (const float*)d_in[0];
    const float* clm = (const float*)d_in[1];
    // d_in[2] = batch_adj: unused by the reference computation
    const float* W   = (const float*)d_in[3];
    float* out = (float*)d_out;
    char*  ws  = (char*)d_ws;

    h16* xh = (h16*)(ws);                            // 8 MB
    h16* xl = (h16*)(ws + (8ull << 20));             // 8 MB
    h16* th = (h16*)(ws + (16ull << 20));            // 8 MB
    h16* wh = (h16*)(ws + (24ull << 20));            // 384 KB
    float2* part = (float2*)(ws + (25ull << 20));    // 16384 rows * 16 chunks * 8B = 2 MB

    convert_all<<<4288, 256, 0, stream>>>(tgt, clm, W, xh, xl, wh);

    for (int L = 0; L < 3; ++L) {
        float* at = out + OFF_AT + (size_t)L * 16777216ull;
        float* nr = out + OFF_NR + (size_t)L * 4194304ull;
        gemm_ct<<<832, 256, 0, stream>>>(xh, xl, wh + (size_t)L * 65536, at, part, th);
        gemm_pv<<<1024, 256, 0, stream>>>(at, th, part, xh, xl, nr, out, L == 2);
    }
}

// Round 6
// 254.660 us; speedup vs baseline: 1.7060x; 1.2015x over previous
//
#include <hip/hip_runtime.h>

// ---------- types ----------
typedef _Float16 h16;
typedef _Float16 h16x8 __attribute__((ext_vector_type(8)));
typedef _Float16 h16x4 __attribute__((ext_vector_type(4)));
typedef float    f32x4 __attribute__((ext_vector_type(4)));

#define NBATCH 16
#define LROWS  1024
#define FDIM   256

// d_out element offsets (fp32 elements)
#define OFF_TGT 0ull
#define OFF_CLM 1048576ull
#define OFF_NR  4194304ull     // + layer*4194304
#define OFF_AT  16777216ull    // + layer*16777216

__device__ __forceinline__ void split2(float x, h16& h, h16& l) {
    h = (h16)x;
    l = (h16)(x - (float)h);
}

// global_load_lds width-16 helper (dest = wave-uniform base + lane*16)
typedef const __attribute__((address_space(1))) void gvoid;
typedef __attribute__((address_space(3))) void lvoid;
__device__ __forceinline__ void gl_lds16(const void* g, void* l) {
    __builtin_amdgcn_global_load_lds((gvoid*)g, (lvoid*)l, 16, 0, 0);
}

// upper-triangle tile enumeration (36 pairs, it <= jt, 8x8 tiles)
__device__ const unsigned char TRI_I[36] = {
    0,0,0,0,0,0,0,0, 1,1,1,1,1,1,1, 2,2,2,2,2,2, 3,3,3,3,3, 4,4,4,4, 5,5,5, 6,6, 7};
__device__ const unsigned char TRI_J[36] = {
    0,1,2,3,4,5,6,7, 1,2,3,4,5,6,7, 2,3,4,5,6,7, 3,4,5,6,7, 4,5,6,7, 5,6,7, 6,7, 7};

// ---------- init: concat(target,claim) -> x hi/lo fp16 ; W -> hi fp16 ----------
__global__ __launch_bounds__(256) void convert_all(const float* __restrict__ tgt,
                                                   const float* __restrict__ clm,
                                                   const float* __restrict__ W,
                                                   h16* __restrict__ xh, h16* __restrict__ xl,
                                                   h16* __restrict__ wh) {
    int bid = blockIdx.x;
    if (bid < 4096) {
        size_t e = ((size_t)bid * 256 + threadIdx.x) * 4;
        int b  = (int)(e >> 18);
        int rf = (int)(e & 262143);
        int r  = rf >> 8, f = rf & 255;
        const float* src = (r < 256)
            ? tgt + ((size_t)b << 16) + ((size_t)r << 8) + f
            : clm + (size_t)b * 196608 + ((size_t)(r - 256) << 8) + f;
        f32x4 v = *(const f32x4*)src;
        h16x4 hv, lv;
#pragma unroll
        for (int j = 0; j < 4; ++j) { h16 hh, ll; split2(v[j], hh, ll); hv[j] = hh; lv[j] = ll; }
        *(h16x4*)(xh + e) = hv;
        *(h16x4*)(xl + e) = lv;
    } else {
        size_t e = ((size_t)(bid - 4096) * 256 + threadIdx.x) * 4;
        f32x4 v = *(const f32x4*)(W + e);
        h16x4 hv;
#pragma unroll
        for (int j = 0; j < 4; ++j) hv[j] = (h16)v[j];
        *(h16x4*)(wh + e) = hv;
    }
}

// ---------- fused corr(symmetric)+trans, BK=32, 32KB LDS, 3/CU ----------
// XCD-aware grid: bid = u*16 + b  ->  batch = bid & 15, unit = bid >> 4.
// All 52 units of a batch land on XCD (b%8): x-slice fetched once per XCD, not 8x.
// u<36 -> corr upper-tri tile (TRI_I,TRI_J); u>=36 -> trans tile.
// corr: 3-term split (ah·bh + ah·bl + al·bh); writes raw logits tile (+transpose
//       if off-diag) + per-(row,64col) (max,sumexp) partials for both orientations.
// trans: 2-term (ah+al)·Wh; store transposed fp16 tT[b][g][l].
__global__ __launch_bounds__(256, 3) void gemm_ct(
    const h16* __restrict__ Xh, const h16* __restrict__ Xl,
    const h16* __restrict__ Wh,
    float* __restrict__ At, float2* __restrict__ part,
    h16* __restrict__ Th) {
    const int b = blockIdx.x & 15;     // XCD-locality: XCD(bid)=bid%8 -> batches b,b+8 per XCD
    const int u = blockIdx.x >> 4;
    const bool isCorr = u < 36;
    int it, jt;
    if (isCorr) { it = TRI_I[u]; jt = TRI_J[u]; }
    else        { int v = u - 36; it = v >> 1; jt = v & 1; }
    const int i0 = it * 128;
    const int j0 = jt * 128;
    const int t  = threadIdx.x;
    const int lane = t & 63, wid = t >> 6;
    const int wr = wid >> 1, wc = wid & 1;

    __shared__ alignas(16) char lds[32768];  // Ah@0 | Al@8K | Bh@16K | Bl@24K, each [128][32]h16

    const size_t arow = ((size_t)b * LROWS + i0) * 256;
    const h16* bHp; const h16* bLp; size_t brow;
    if (isCorr) { bHp = Xh; bLp = Xl; brow = ((size_t)b * LROWS + j0) * 256; }
    else        { bHp = Wh; bLp = Xl; brow = (size_t)j0 * 256; }   // bLp unused for trans

    f32x4 acc[4][4];
#pragma unroll
    for (int i = 0; i < 4; ++i)
#pragma unroll
        for (int j = 0; j < 4; ++j) acc[i][j] = (f32x4){0.f, 0.f, 0.f, 0.f};

    const int grow = t >> 2;   // 0..63 (row within 64-row staging pass)
    const int gq   = t & 3;    // 16B chunk 0..3 within 64B row

    for (int kt = 0; kt < 8; ++kt) {
        __syncthreads();       // prior MFMA done reading LDS
#pragma unroll
        for (int p = 0; p < 2; ++p) {
            int r = p * 64 + grow;
            // pre-swizzled source chunk (involution c ^ ((r>>1)&3)), linear LDS dest
            size_t so = (size_t)r * 256 + kt * 32 + ((gq ^ ((r >> 1) & 3)) << 3);
            char* d = lds + p * 4096 + wid * 1024;
            gl_lds16(Xh + arow + so, d);
            gl_lds16(Xl + arow + so, d + 8192);
            gl_lds16(bHp + brow + so, d + 16384);
            if (isCorr) gl_lds16(bLp + brow + so, d + 24576);
        }
        __syncthreads();       // drains global_load_lds

        const int kq = lane >> 4;                 // global k-chunk 0..3
        const int rA = wr * 64 + (lane & 15);
        const int rB = wc * 64 + (lane & 15);
        h16x8 ah[4], al[4], bh[4], bl[4];
#pragma unroll
        for (int mi = 0; mi < 4; ++mi) {
            int r   = rA + mi * 16;
            int off = r * 64 + ((kq ^ ((r >> 1) & 3)) << 4);
            ah[mi] = *(const h16x8*)(lds + off);
            al[mi] = *(const h16x8*)(lds + 8192 + off);
        }
#pragma unroll
        for (int nj = 0; nj < 4; ++nj) {
            int r   = rB + nj * 16;
            int off = r * 64 + ((kq ^ ((r >> 1) & 3)) << 4);
            bh[nj] = *(const h16x8*)(lds + 16384 + off);
            if (isCorr) bl[nj] = *(const h16x8*)(lds + 24576 + off);
        }
        __builtin_amdgcn_s_setprio(1);
#pragma unroll
        for (int mi = 0; mi < 4; ++mi)
#pragma unroll
            for (int nj = 0; nj < 4; ++nj) {
                acc[mi][nj] = __builtin_amdgcn_mfma_f32_16x16x32_f16(ah[mi], bh[nj], acc[mi][nj], 0, 0, 0);
                acc[mi][nj] = __builtin_amdgcn_mfma_f32_16x16x32_f16(al[mi], bh[nj], acc[mi][nj], 0, 0, 0);
                if (isCorr)
                    acc[mi][nj] = __builtin_amdgcn_mfma_f32_16x16x32_f16(ah[mi], bl[nj], acc[mi][nj], 0, 0, 0);
            }
        __builtin_amdgcn_s_setprio(0);
    }

    const int mBase = i0 + wr * 64;
    const int nBase = j0 + wc * 64;
    if (isCorr) {
        float* Cb = At + (size_t)b * LROWS * 1024;
        // normal tile write
#pragma unroll
        for (int mi = 0; mi < 4; ++mi)
#pragma unroll
            for (int nj = 0; nj < 4; ++nj) {
                int n  = nBase + nj * 16 + (lane & 15);
                int m0 = mBase + mi * 16 + ((lane >> 4) * 4);
#pragma unroll
                for (int rg = 0; rg < 4; ++rg)
                    Cb[(size_t)(m0 + rg) * 1024 + n] = acc[mi][nj][rg];
            }
        // normal row-stats: rows in i-range, chunk in j-range
        {
            const int chunk = jt * 2 + wc;
#pragma unroll
            for (int mi = 0; mi < 4; ++mi)
#pragma unroll
                for (int rg = 0; rg < 4; ++rg) {
                    float v0 = acc[mi][0][rg], v1 = acc[mi][1][rg];
                    float v2 = acc[mi][2][rg], v3 = acc[mi][3][rg];
                    float mx = fmaxf(fmaxf(v0, v1), fmaxf(v2, v3));
#pragma unroll
                    for (int off = 8; off >= 1; off >>= 1) mx = fmaxf(mx, __shfl_xor(mx, off, 64));
                    float s = __expf(v0 - mx) + __expf(v1 - mx) + __expf(v2 - mx) + __expf(v3 - mx);
#pragma unroll
                    for (int off = 8; off >= 1; off >>= 1) s += __shfl_xor(s, off, 64);
                    if ((lane & 15) == 0) {
                        int row = mBase + mi * 16 + ((lane >> 4) * 4) + rg;
                        part[((size_t)b * 1024 + row) * 16 + chunk] = make_float2(mx, s);
                    }
                }
        }
        if (it != jt) {
            // transposed tile write: At[n][m]
#pragma unroll
            for (int mi = 0; mi < 4; ++mi)
#pragma unroll
                for (int nj = 0; nj < 4; ++nj) {
                    int n  = nBase + nj * 16 + (lane & 15);
                    int m0 = mBase + mi * 16 + ((lane >> 4) * 4);
                    f32x4 vv = acc[mi][nj];
                    *(f32x4*)(Cb + (size_t)n * 1024 + m0) = vv;
                }
            // transposed stats: rows in j-range (n), chunk in i-range
            const int chunk = it * 2 + wr;
#pragma unroll
            for (int nj = 0; nj < 4; ++nj) {
                float mx = -3.0e38f;
#pragma unroll
                for (int mi = 0; mi < 4; ++mi)
#pragma unroll
                    for (int rg = 0; rg < 4; ++rg) mx = fmaxf(mx, acc[mi][nj][rg]);
                mx = fmaxf(mx, __shfl_xor(mx, 16, 64));
                mx = fmaxf(mx, __shfl_xor(mx, 32, 64));
                float s = 0.f;
#pragma unroll
                for (int mi = 0; mi < 4; ++mi)
#pragma unroll
                    for (int rg = 0; rg < 4; ++rg) s += __expf(acc[mi][nj][rg] - mx);
                s += __shfl_xor(s, 16, 64);
                s += __shfl_xor(s, 32, 64);
                if (lane < 16) {
                    int n = nBase + nj * 16 + lane;
                    part[((size_t)b * 1024 + n) * 16 + chunk] = make_float2(mx, s);
                }
            }
        }
    } else {
        // store t transposed, plain fp16
#pragma unroll
        for (int mi = 0; mi < 4; ++mi)
#pragma unroll
            for (int nj = 0; nj < 4; ++nj) {
                int n  = nBase + nj * 16 + (lane & 15);
                int m0 = mBase + mi * 16 + ((lane >> 4) * 4);
                h16x4 hv;
#pragma unroll
                for (int rg = 0; rg < 4; ++rg) hv[rg] = (h16)acc[mi][nj][rg];
                size_t off = ((size_t)b * 256 + n) * 1024 + m0;  // tT[b][g][l]
                *(h16x4*)(Th + off) = hv;
            }
    }
}

// ---------- PV fused: stats reduce + p = exp(l-M)/S in place + Node = relu(x + p·t) ----------
// M-tile 16, N full 256 (4 waves x 64-col quadrants), K=1024, Kt=64. 1024 blocks, 4/CU.
__global__ __launch_bounds__(256, 4) void gemm_pv(
    float* __restrict__ At,                        // logits in, normalized p out (in place)
    const h16* __restrict__ Th,
    const float2* __restrict__ part,
    h16* __restrict__ Xh, h16* __restrict__ Xl,
    float* __restrict__ NodeOut, float* __restrict__ OutBase, int last) {
    const int id   = blockIdx.x;
    const int xcd  = id & 7, rest = id >> 3;       // 1024 blocks
    const int b    = (xcd << 1) | (rest & 1);      // same-b blocks share HW XCD -> tT in L2
    const int mt   = rest >> 1;                    // 0..63
    const int i0   = mt * 16;
    const int t    = threadIdx.x;
    const int lane = t & 63, wid = t >> 6;
    const int wc   = wid;                          // n-quadrant 0..3

    __shared__ alignas(16) char lds[34816];
    // A [16][64]h16 @0 (2K, swizzled) | B [256][64]h16 @2048 (32K)
    __shared__ float2 sst[16];

    // stats prologue: reduce this block's 16 rows' 16 chunk partials
    if (t < 16) {
        const float2* pp = part + ((size_t)b * 1024 + i0 + t) * 16;
        float2 v[16];
        float M = -3.0e38f;
#pragma unroll
        for (int c = 0; c < 16; ++c) { v[c] = pp[c]; M = fmaxf(M, v[c].x); }
        float S = 0.f;
#pragma unroll
        for (int c = 0; c < 16; ++c) S += v[c].y * __expf(v[c].x - M);
        sst[t] = make_float2(M, 1.0f / S);
    }
    __syncthreads();

    float* Arow = At + ((size_t)b * LROWS + i0) * 1024;
    const size_t tbase = (size_t)b * 256 * 1024;

    const int ar0 = t >> 4;      // staging row 0..15
    const int aq  = t & 15;
    float2 st0 = sst[ar0];

    f32x4 acc[4];
#pragma unroll
    for (int i = 0; i < 4; ++i) acc[i] = (f32x4){0.f, 0.f, 0.f, 0.f};

    const int bgrow = t >> 3;    // 0..31
    const int bq    = t & 7;

    for (int kt = 0; kt < 16; ++kt) {
        // A logits load (global only — safe before barrier)
        f32x4 va0 = *(const f32x4*)(Arow + (size_t)ar0 * 1024 + kt * 64 + aq * 4);
        __syncthreads();         // prior MFMA done reading LDS

        // B: async global->LDS, pre-swizzled per-lane source, linear dest
#pragma unroll
        for (int itr = 0; itr < 8; ++itr) {
            int g = itr * 32 + bgrow;
            size_t so = tbase + (size_t)g * 1024 + kt * 64 + ((bq ^ (g & 7)) << 3);
            char* d = lds + 2048 + itr * 4096 + wid * 1024;
            gl_lds16(Th + so, d);
        }

        // p = exp(v - M) * invS; write back in place; stage A fp16 to LDS (swizzled write)
        f32x4 p0;
#pragma unroll
        for (int e = 0; e < 4; ++e) p0[e] = __expf(va0[e] - st0.x) * st0.y;
        *(f32x4*)(Arow + (size_t)ar0 * 1024 + kt * 64 + aq * 4) = p0;
        h16x4 h0;
#pragma unroll
        for (int e = 0; e < 4; ++e) h0[e] = (h16)p0[e];
        {
            int c = aq >> 1, hb = (aq & 1) * 8;
            int o0 = ar0 * 128 + ((c ^ (ar0 & 7)) * 16) + hb;
            *(h16x4*)(lds + o0) = h0;
        }
        __syncthreads();         // drains ds_writes + global_load_lds

        const int kq = lane >> 4;
        const int rA = lane & 15;
        __builtin_amdgcn_s_setprio(1);
#pragma unroll
        for (int s = 0; s < 2; ++s) {
            int ca = ((s * 4 + kq) ^ (rA & 7)) * 16;
            h16x8 ah = *(const h16x8*)(lds + rA * 128 + ca);
#pragma unroll
            for (int nf = 0; nf < 4; ++nf) {
                int g  = wc * 64 + nf * 16 + (lane & 15);
                int cb = ((s * 4 + kq) ^ (g & 7)) * 16;
                h16x8 bh = *(const h16x8*)(lds + 2048 + g * 128 + cb);
                acc[nf] = __builtin_amdgcn_mfma_f32_16x16x32_f16(ah, bh, acc[nf], 0, 0, 0);
            }
        }
        __builtin_amdgcn_s_setprio(0);
    }

    // epilogue: residual + relu, update x hi/lo, write node (+final slices)
#pragma unroll
    for (int nf = 0; nf < 4; ++nf) {
        int n = wc * 64 + nf * 16 + (lane & 15);
#pragma unroll
        for (int rg = 0; rg < 4; ++rg) {
            int m = i0 + ((lane >> 4) * 4) + rg;
            size_t off = ((size_t)b * LROWS + m) * FDIM + n;
            float res = (float)Xh[off] + (float)Xl[off];
            float y   = res + acc[nf][rg];
            y = y > 0.f ? y : 0.f;
            NodeOut[off] = y;
            h16 hh, ll; split2(y, hh, ll);
            Xh[off] = hh; Xl[off] = ll;
            if (last) {
                float* dst = (m < 256)
                    ? OutBase + OFF_TGT + ((size_t)b << 16) + ((size_t)m << 8) + n
                    : OutBase + OFF_CLM + (size_t)b * 196608 + ((size_t)(m - 256) << 8) + n;
                *dst = y;
            }
        }
    }
}

// ---------- host ----------
extern "C" void kernel_launch(void* const* d_in, const int* in_sizes, int n_in,
                              void* d_out, int out_size, void* d_ws, size_t ws_size,
                              hipStream_t stream) {
    (void)in_sizes; (void)n_in; (void)out_size; (void)ws_size;
    const float* tgt = (const float*)d_in[0];
    const float* clm = (const float*)d_in[1];
    // d_in[2] = batch_adj: unused by the reference computation
    const float* W   = (const float*)d_in[3];
    float* out = (float*)d_out;
    char*  ws  = (char*)d_ws;

    h16* xh = (h16*)(ws);                            // 8 MB
    h16* xl = (h16*)(ws + (8ull << 20));             // 8 MB
    h16* th = (h16*)(ws + (16ull << 20));            // 8 MB
    h16* wh = (h16*)(ws + (24ull << 20));            // 384 KB
    float2* part = (float2*)(ws + (25ull << 20));    // 16384 rows * 16 chunks * 8B = 2 MB

    convert_all<<<4288, 256, 0, stream>>>(tgt, clm, W, xh, xl, wh);

    for (int L = 0; L < 3; ++L) {
        float* at = out + OFF_AT + (size_t)L * 16777216ull;
        float* nr = out + OFF_NR + (size_t)L * 4194304ull;
        gemm_ct<<<832, 256, 0, stream>>>(xh, xl, wh + (size_t)L * 65536, at, part, th);
        gemm_pv<<<1024, 256, 0, stream>>>(at, th, part, xh, xl, nr, out, L == 2);
    }
}

// Round 7
// 227.635 us; speedup vs baseline: 1.9085x; 1.1187x over previous
//
#include <hip/hip_runtime.h>

// ---------- types ----------
typedef _Float16 h16;
typedef _Float16 h16x8 __attribute__((ext_vector_type(8)));
typedef _Float16 h16x4 __attribute__((ext_vector_type(4)));
typedef float    f32x4 __attribute__((ext_vector_type(4)));

#define NBATCH 16
#define LROWS  1024
#define FDIM   256

// d_out element offsets (fp32 elements)
#define OFF_TGT 0ull
#define OFF_CLM 1048576ull
#define OFF_NR  4194304ull     // + layer*4194304
#define OFF_AT  16777216ull    // + layer*16777216

__device__ __forceinline__ void split2(float x, h16& h, h16& l) {
    h = (h16)x;
    l = (h16)(x - (float)h);
}

// global_load_lds width-16 helper (dest = wave-uniform base + lane*16)
typedef const __attribute__((address_space(1))) void gvoid;
typedef __attribute__((address_space(3))) void lvoid;
__device__ __forceinline__ void gl_lds16(const void* g, void* l) {
    __builtin_amdgcn_global_load_lds((gvoid*)g, (lvoid*)l, 16, 0, 0);
}

// upper-triangle tile enumeration (36 pairs, it <= jt, 8x8 tiles)
__device__ const unsigned char TRI_I[36] = {
    0,0,0,0,0,0,0,0, 1,1,1,1,1,1,1, 2,2,2,2,2,2, 3,3,3,3,3, 4,4,4,4, 5,5,5, 6,6, 7};
__device__ const unsigned char TRI_J[36] = {
    0,1,2,3,4,5,6,7, 1,2,3,4,5,6,7, 2,3,4,5,6,7, 3,4,5,6,7, 4,5,6,7, 5,6,7, 6,7, 7};

// ---------- init: concat(target,claim) -> x hi/lo fp16 ; W -> hi fp16 ----------
__global__ __launch_bounds__(256) void convert_all(const float* __restrict__ tgt,
                                                   const float* __restrict__ clm,
                                                   const float* __restrict__ W,
                                                   h16* __restrict__ xh, h16* __restrict__ xl,
                                                   h16* __restrict__ wh) {
    int bid = blockIdx.x;
    if (bid < 4096) {
        size_t e = ((size_t)bid * 256 + threadIdx.x) * 4;
        int b  = (int)(e >> 18);
        int rf = (int)(e & 262143);
        int r  = rf >> 8, f = rf & 255;
        const float* src = (r < 256)
            ? tgt + ((size_t)b << 16) + ((size_t)r << 8) + f
            : clm + (size_t)b * 196608 + ((size_t)(r - 256) << 8) + f;
        f32x4 v = *(const f32x4*)src;
        h16x4 hv, lv;
#pragma unroll
        for (int j = 0; j < 4; ++j) { h16 hh, ll; split2(v[j], hh, ll); hv[j] = hh; lv[j] = ll; }
        *(h16x4*)(xh + e) = hv;
        *(h16x4*)(xl + e) = lv;
    } else {
        size_t e = ((size_t)(bid - 4096) * 256 + threadIdx.x) * 4;
        f32x4 v = *(const f32x4*)(W + e);
        h16x4 hv;
#pragma unroll
        for (int j = 0; j < 4; ++j) hv[j] = (h16)v[j];
        *(h16x4*)(wh + e) = hv;
    }
}

// ---------- fused corr(symmetric)+trans, BK=32, 32KB LDS, 3/CU ----------
// XCD-aware grid: batch = bid & 15, unit = bid >> 4 (all units of a batch on one XCD).
// corr (u<36): 3-term split logits; writes p_tilde = exp(v - m_chunk) fp16 for BOTH
//   orientations + per-(row,64col-chunk) (max,sumexp) partials for both orientations.
// trans (u>=36): 2-term (ah+al)·Wh; store transposed fp16 tT[b][g][l].
__global__ __launch_bounds__(256, 3) void gemm_ct(
    const h16* __restrict__ Xh, const h16* __restrict__ Xl,
    const h16* __restrict__ Wh,
    h16* __restrict__ Ptil, float2* __restrict__ part,
    h16* __restrict__ Th) {
    const int b = blockIdx.x & 15;
    const int u = blockIdx.x >> 4;
    const bool isCorr = u < 36;
    int it, jt;
    if (isCorr) { it = TRI_I[u]; jt = TRI_J[u]; }
    else        { int v = u - 36; it = v >> 1; jt = v & 1; }
    const int i0 = it * 128;
    const int j0 = jt * 128;
    const int t  = threadIdx.x;
    const int lane = t & 63, wid = t >> 6;
    const int wr = wid >> 1, wc = wid & 1;

    __shared__ alignas(16) char lds[32768];  // Ah@0 | Al@8K | Bh@16K | Bl@24K, each [128][32]h16

    const size_t arow = ((size_t)b * LROWS + i0) * 256;
    const h16* bHp; const h16* bLp; size_t brow;
    if (isCorr) { bHp = Xh; bLp = Xl; brow = ((size_t)b * LROWS + j0) * 256; }
    else        { bHp = Wh; bLp = Xl; brow = (size_t)j0 * 256; }   // bLp unused for trans

    f32x4 acc[4][4];
#pragma unroll
    for (int i = 0; i < 4; ++i)
#pragma unroll
        for (int j = 0; j < 4; ++j) acc[i][j] = (f32x4){0.f, 0.f, 0.f, 0.f};

    const int grow = t >> 2;   // 0..63
    const int gq   = t & 3;    // 16B chunk within 64B row

    for (int kt = 0; kt < 8; ++kt) {
        __syncthreads();       // prior MFMA done reading LDS
#pragma unroll
        for (int p = 0; p < 2; ++p) {
            int r = p * 64 + grow;
            size_t so = (size_t)r * 256 + kt * 32 + ((gq ^ ((r >> 1) & 3)) << 3);
            char* d = lds + p * 4096 + wid * 1024;
            gl_lds16(Xh + arow + so, d);
            gl_lds16(Xl + arow + so, d + 8192);
            gl_lds16(bHp + brow + so, d + 16384);
            if (isCorr) gl_lds16(bLp + brow + so, d + 24576);
        }
        __syncthreads();       // drains global_load_lds

        const int kq = lane >> 4;
        const int rA = wr * 64 + (lane & 15);
        const int rB = wc * 64 + (lane & 15);
        h16x8 ah[4], al[4], bh[4], bl[4];
#pragma unroll
        for (int mi = 0; mi < 4; ++mi) {
            int r   = rA + mi * 16;
            int off = r * 64 + ((kq ^ ((r >> 1) & 3)) << 4);
            ah[mi] = *(const h16x8*)(lds + off);
            al[mi] = *(const h16x8*)(lds + 8192 + off);
        }
#pragma unroll
        for (int nj = 0; nj < 4; ++nj) {
            int r   = rB + nj * 16;
            int off = r * 64 + ((kq ^ ((r >> 1) & 3)) << 4);
            bh[nj] = *(const h16x8*)(lds + 16384 + off);
            if (isCorr) bl[nj] = *(const h16x8*)(lds + 24576 + off);
        }
        __builtin_amdgcn_s_setprio(1);
#pragma unroll
        for (int mi = 0; mi < 4; ++mi)
#pragma unroll
            for (int nj = 0; nj < 4; ++nj) {
                acc[mi][nj] = __builtin_amdgcn_mfma_f32_16x16x32_f16(ah[mi], bh[nj], acc[mi][nj], 0, 0, 0);
                acc[mi][nj] = __builtin_amdgcn_mfma_f32_16x16x32_f16(al[mi], bh[nj], acc[mi][nj], 0, 0, 0);
                if (isCorr)
                    acc[mi][nj] = __builtin_amdgcn_mfma_f32_16x16x32_f16(ah[mi], bl[nj], acc[mi][nj], 0, 0, 0);
            }
        __builtin_amdgcn_s_setprio(0);
    }

    const int mBase = i0 + wr * 64;
    const int nBase = j0 + wc * 64;
    if (isCorr) {
        h16* Pb = Ptil + (size_t)b * LROWS * 1024;
        // normal orientation: stats + p_tilde (rows i-range, chunk jt*2+wc)
        {
            const int chunk = jt * 2 + wc;
#pragma unroll
            for (int mi = 0; mi < 4; ++mi)
#pragma unroll
                for (int rg = 0; rg < 4; ++rg) {
                    float v0 = acc[mi][0][rg], v1 = acc[mi][1][rg];
                    float v2 = acc[mi][2][rg], v3 = acc[mi][3][rg];
                    float mx = fmaxf(fmaxf(v0, v1), fmaxf(v2, v3));
#pragma unroll
                    for (int off = 8; off >= 1; off >>= 1) mx = fmaxf(mx, __shfl_xor(mx, off, 64));
                    float e0 = __expf(v0 - mx), e1 = __expf(v1 - mx);
                    float e2 = __expf(v2 - mx), e3 = __expf(v3 - mx);
                    float s = e0 + e1 + e2 + e3;
#pragma unroll
                    for (int off = 8; off >= 1; off >>= 1) s += __shfl_xor(s, off, 64);
                    int row = mBase + mi * 16 + ((lane >> 4) * 4) + rg;
                    if ((lane & 15) == 0)
                        part[((size_t)b * 1024 + row) * 16 + chunk] = make_float2(mx, s);
                    size_t rb = (size_t)row * 1024 + nBase + (lane & 15);
                    Pb[rb]      = (h16)e0;
                    Pb[rb + 16] = (h16)e1;
                    Pb[rb + 32] = (h16)e2;
                    Pb[rb + 48] = (h16)e3;
                }
        }
        if (it != jt) {
            // transposed orientation: rows j-range (n), chunk in i-range
            const int chunk = it * 2 + wr;
#pragma unroll
            for (int nj = 0; nj < 4; ++nj) {
                float mx = -3.0e38f;
#pragma unroll
                for (int mi = 0; mi < 4; ++mi)
#pragma unroll
                    for (int rg = 0; rg < 4; ++rg) mx = fmaxf(mx, acc[mi][nj][rg]);
                mx = fmaxf(mx, __shfl_xor(mx, 16, 64));
                mx = fmaxf(mx, __shfl_xor(mx, 32, 64));
                float s = 0.f;
                h16x4 pt[4];
#pragma unroll
                for (int mi = 0; mi < 4; ++mi)
#pragma unroll
                    for (int rg = 0; rg < 4; ++rg) {
                        float e = __expf(acc[mi][nj][rg] - mx);
                        s += e;
                        pt[mi][rg] = (h16)e;
                    }
                s += __shfl_xor(s, 16, 64);
                s += __shfl_xor(s, 32, 64);
                int n = nBase + nj * 16 + (lane & 15);
                if (lane < 16)
                    part[((size_t)b * 1024 + n) * 16 + chunk] = make_float2(mx, s);
                size_t nb = (size_t)n * 1024 + mBase + ((lane >> 4) * 4);
#pragma unroll
                for (int mi = 0; mi < 4; ++mi)
                    *(h16x4*)(Pb + nb + mi * 16) = pt[mi];
            }
        }
    } else {
        // store t transposed, plain fp16
#pragma unroll
        for (int mi = 0; mi < 4; ++mi)
#pragma unroll
            for (int nj = 0; nj < 4; ++nj) {
                int n  = nBase + nj * 16 + (lane & 15);
                int m0 = mBase + mi * 16 + ((lane >> 4) * 4);
                h16x4 hv;
#pragma unroll
                for (int rg = 0; rg < 4; ++rg) hv[rg] = (h16)acc[mi][nj][rg];
                size_t off = ((size_t)b * 256 + n) * 1024 + m0;  // tT[b][g][l]
                *(h16x4*)(Th + off) = hv;
            }
    }
}

// ---------- PV: p = p_tilde * exp(m_chunk - M)/S; At=p (fp32); Node = relu(x + p·t) ----------
// M-tile 32, N full 256 (4 waves x 64-col quadrants), K=1024, Kt=64. 512 blocks, 4/CU.
__global__ __launch_bounds__(256, 4) void gemm_pv(
    const h16* __restrict__ Ptil, const float2* __restrict__ part,
    float* __restrict__ At,
    const h16* __restrict__ Th,
    h16* __restrict__ Xh, h16* __restrict__ Xl,
    float* __restrict__ NodeOut, float* __restrict__ OutBase, int last) {
    const int id   = blockIdx.x;
    const int xcd  = id & 7, rest = id >> 3;       // 512 blocks
    const int b    = (xcd << 1) | (rest & 1);      // same-b blocks share HW XCD -> tT in L2
    const int mt   = rest >> 1;                    // 0..31
    const int i0   = mt * 32;
    const int t    = threadIdx.x;
    const int lane = t & 63, wid = t >> 6;
    const int wc   = wid;                          // n-quadrant 0..3

    __shared__ alignas(16) char lds[38912];
    // A [32][64]h16 @0 (4K, swizzled) | B [256][64]h16 @4096 (32K) | sc [32][16]f32 @36864 (2K)
    float* sc = (float*)(lds + 36864);

    // stats prologue: per-row M,S then per-(row,chunk) scale
    if (t < 32) {
        const float2* pp = part + ((size_t)b * 1024 + i0 + t) * 16;
        float2 v[16];
        float M = -3.0e38f;
#pragma unroll
        for (int c = 0; c < 16; ++c) { v[c] = pp[c]; M = fmaxf(M, v[c].x); }
        float S = 0.f;
#pragma unroll
        for (int c = 0; c < 16; ++c) S += v[c].y * __expf(v[c].x - M);
        float inv = 1.0f / S;
#pragma unroll
        for (int c = 0; c < 16; ++c) sc[t * 16 + c] = __expf(v[c].x - M) * inv;
    }
    __syncthreads();

    const h16* Prow = Ptil + ((size_t)b * LROWS + i0) * 1024;
    float* Arow = At + ((size_t)b * LROWS + i0) * 1024;
    const size_t tbase = (size_t)b * 256 * 1024;

    const int ar = t >> 3;       // 0..31 (A row / B row-group)
    const int ac = t & 7;        // 8-col group

    f32x4 acc[2][4];
#pragma unroll
    for (int i = 0; i < 2; ++i)
#pragma unroll
        for (int j = 0; j < 4; ++j) acc[i][j] = (f32x4){0.f, 0.f, 0.f, 0.f};

    for (int kt = 0; kt < 16; ++kt) {
        // A: p_tilde fp16 load + per-chunk scale (global/LDS-sc reads — before barrier is fine)
        h16x8 pt = *(const h16x8*)(Prow + (size_t)ar * 1024 + kt * 64 + ac * 8);
        float s  = sc[ar * 16 + kt];
        __syncthreads();         // prior MFMA done reading LDS A/B

        // B: async global->LDS, pre-swizzled per-lane source, linear dest
#pragma unroll
        for (int itr = 0; itr < 8; ++itr) {
            int g = itr * 32 + ar;
            size_t so = tbase + (size_t)g * 1024 + kt * 64 + ((ac ^ (g & 7)) << 3);
            char* d = lds + 4096 + itr * 4096 + wid * 1024;
            gl_lds16(Th + so, d);
        }

        // normalize: write fp32 attn to d_out, stage fp16 product to LDS
        f32x4 plo, phi;
#pragma unroll
        for (int e = 0; e < 4; ++e) plo[e] = (float)pt[e] * s;
#pragma unroll
        for (int e = 0; e < 4; ++e) phi[e] = (float)pt[4 + e] * s;
        *(f32x4*)(Arow + (size_t)ar * 1024 + kt * 64 + ac * 8)     = plo;
        *(f32x4*)(Arow + (size_t)ar * 1024 + kt * 64 + ac * 8 + 4) = phi;
        h16x8 a16;
#pragma unroll
        for (int e = 0; e < 4; ++e) { a16[e] = (h16)plo[e]; a16[4 + e] = (h16)phi[e]; }
        *(h16x8*)(lds + ar * 128 + ((ac ^ (ar & 7)) << 4)) = a16;
        __syncthreads();         // drains ds_writes + global_load_lds

        const int kq = lane >> 4;
        __builtin_amdgcn_s_setprio(1);
#pragma unroll
        for (int s2 = 0; s2 < 2; ++s2) {
            h16x8 ah[2], bh[4];
#pragma unroll
            for (int mi = 0; mi < 2; ++mi) {
                int r = mi * 16 + (lane & 15);
                ah[mi] = *(const h16x8*)(lds + r * 128 + (((s2 * 4 + kq) ^ (r & 7)) << 4));
            }
#pragma unroll
            for (int nf = 0; nf < 4; ++nf) {
                int g = wc * 64 + nf * 16 + (lane & 15);
                bh[nf] = *(const h16x8*)(lds + 4096 + g * 128 + (((s2 * 4 + kq) ^ (g & 7)) << 4));
            }
#pragma unroll
            for (int mi = 0; mi < 2; ++mi)
#pragma unroll
                for (int nf = 0; nf < 4; ++nf)
                    acc[mi][nf] = __builtin_amdgcn_mfma_f32_16x16x32_f16(ah[mi], bh[nf], acc[mi][nf], 0, 0, 0);
        }
        __builtin_amdgcn_s_setprio(0);
    }

    // epilogue: residual + relu, update x hi/lo, write node (+final slices)
#pragma unroll
    for (int mi = 0; mi < 2; ++mi)
#pragma unroll
        for (int nf = 0; nf < 4; ++nf) {
            int n = wc * 64 + nf * 16 + (lane & 15);
#pragma unroll
            for (int rg = 0; rg < 4; ++rg) {
                int m = i0 + mi * 16 + ((lane >> 4) * 4) + rg;
                size_t off = ((size_t)b * LROWS + m) * FDIM + n;
                float res = (float)Xh[off] + (float)Xl[off];
                float y   = res + acc[mi][nf][rg];
                y = y > 0.f ? y : 0.f;
                NodeOut[off] = y;
                h16 hh, ll; split2(y, hh, ll);
                Xh[off] = hh; Xl[off] = ll;
                if (last) {
                    float* dst = (m < 256)
                        ? OutBase + OFF_TGT + ((size_t)b << 16) + ((size_t)m << 8) + n
                        : OutBase + OFF_CLM + (size_t)b * 196608 + ((size_t)(m - 256) << 8) + n;
                    *dst = y;
                }
            }
        }
}

// ---------- host ----------
extern "C" void kernel_launch(void* const* d_in, const int* in_sizes, int n_in,
                              void* d_out, int out_size, void* d_ws, size_t ws_size,
                              hipStream_t stream) {
    (void)in_sizes; (void)n_in; (void)out_size; (void)ws_size;
    const float* tgt = (const float*)d_in[0];
    const float* clm = (const float*)d_in[1];
    // d_in[2] = batch_adj: unused by the reference computation
    const float* W   = (const float*)d_in[3];
    float* out = (float*)d_out;
    char*  ws  = (char*)d_ws;

    h16* xh = (h16*)(ws);                            // 8 MB
    h16* xl = (h16*)(ws + (8ull << 20));             // 8 MB
    h16* th = (h16*)(ws + (16ull << 20));            // 8 MB
    h16* wh = (h16*)(ws + (24ull << 20));            // 384 KB
    float2* part = (float2*)(ws + (25ull << 20));    // 2 MB
    h16* ptil = (h16*)(ws + (27ull << 20));          // 32 MB: p_tilde fp16 [16][1024][1024]

    convert_all<<<4288, 256, 0, stream>>>(tgt, clm, W, xh, xl, wh);

    for (int L = 0; L < 3; ++L) {
        float* at = out + OFF_AT + (size_t)L * 16777216ull;
        float* nr = out + OFF_NR + (size_t)L * 4194304ull;
        gemm_ct<<<832, 256, 0, stream>>>(xh, xl, wh + (size_t)L * 65536, ptil, part, th);
        gemm_pv<<<512, 256, 0, stream>>>(ptil, part, at, th, xh, xl, nr, out, L == 2);
    }
}

// Round 8
// 227.101 us; speedup vs baseline: 1.9130x; 1.0023x over previous
//
#include <hip/hip_runtime.h>

// ---------- types ----------
typedef _Float16 h16;
typedef _Float16 h16x8 __attribute__((ext_vector_type(8)));
typedef _Float16 h16x4 __attribute__((ext_vector_type(4)));
typedef float    f32x4 __attribute__((ext_vector_type(4)));

#define NBATCH 16
#define LROWS  1024
#define FDIM   256

// d_out element offsets (fp32 elements)
#define OFF_TGT 0ull
#define OFF_CLM 1048576ull
#define OFF_NR  4194304ull     // + layer*4194304
#define OFF_AT  16777216ull    // + layer*16777216

__device__ __forceinline__ void split2(float x, h16& h, h16& l) {
    h = (h16)x;
    l = (h16)(x - (float)h);
}

// global_load_lds width-16 helper (dest = wave-uniform base + lane*16)
typedef const __attribute__((address_space(1))) void gvoid;
typedef __attribute__((address_space(3))) void lvoid;
__device__ __forceinline__ void gl_lds16(const void* g, void* l) {
    __builtin_amdgcn_global_load_lds((gvoid*)g, (lvoid*)l, 16, 0, 0);
}

// upper-triangle tile enumeration (36 pairs, it <= jt, 8x8 tiles)
__device__ const unsigned char TRI_I[36] = {
    0,0,0,0,0,0,0,0, 1,1,1,1,1,1,1, 2,2,2,2,2,2, 3,3,3,3,3, 4,4,4,4, 5,5,5, 6,6, 7};
__device__ const unsigned char TRI_J[36] = {
    0,1,2,3,4,5,6,7, 1,2,3,4,5,6,7, 2,3,4,5,6,7, 3,4,5,6,7, 4,5,6,7, 5,6,7, 6,7, 7};

// ---------- init: concat(target,claim) -> x hi/lo fp16 ; W -> hi fp16 ----------
__global__ __launch_bounds__(256) void convert_all(const float* __restrict__ tgt,
                                                   const float* __restrict__ clm,
                                                   const float* __restrict__ W,
                                                   h16* __restrict__ xh, h16* __restrict__ xl,
                                                   h16* __restrict__ wh) {
    int bid = blockIdx.x;
    if (bid < 4096) {
        size_t e = ((size_t)bid * 256 + threadIdx.x) * 4;
        int b  = (int)(e >> 18);
        int rf = (int)(e & 262143);
        int r  = rf >> 8, f = rf & 255;
        const float* src = (r < 256)
            ? tgt + ((size_t)b << 16) + ((size_t)r << 8) + f
            : clm + (size_t)b * 196608 + ((size_t)(r - 256) << 8) + f;
        f32x4 v = *(const f32x4*)src;
        h16x4 hv, lv;
#pragma unroll
        for (int j = 0; j < 4; ++j) { h16 hh, ll; split2(v[j], hh, ll); hv[j] = hh; lv[j] = ll; }
        *(h16x4*)(xh + e) = hv;
        *(h16x4*)(xl + e) = lv;
    } else {
        size_t e = ((size_t)(bid - 4096) * 256 + threadIdx.x) * 4;
        f32x4 v = *(const f32x4*)(W + e);
        h16x4 hv;
#pragma unroll
        for (int j = 0; j < 4; ++j) hv[j] = (h16)v[j];
        *(h16x4*)(wh + e) = hv;
    }
}

// ---------- fused corr(symmetric)+trans, BK=32, 32KB LDS, 3/CU ----------
// XCD-aware grid: batch = bid & 15, unit = bid >> 4 (all units of a batch on one XCD).
// corr (u<36): 3-term split logits; writes p_tilde = exp(v - m_chunk) fp16 for BOTH
//   orientations + per-(row,64col-chunk) (max,sumexp) partials for both orientations.
// trans (u>=36): 2-term (ah+al)·Wh; store transposed fp16 tT[b][g][l].
__global__ __launch_bounds__(256, 3) void gemm_ct(
    const h16* __restrict__ Xh, const h16* __restrict__ Xl,
    const h16* __restrict__ Wh,
    h16* __restrict__ Ptil, float2* __restrict__ part,
    h16* __restrict__ Th) {
    const int b = blockIdx.x & 15;
    const int u = blockIdx.x >> 4;
    const bool isCorr = u < 36;
    int it, jt;
    if (isCorr) { it = TRI_I[u]; jt = TRI_J[u]; }
    else        { int v = u - 36; it = v >> 1; jt = v & 1; }
    const int i0 = it * 128;
    const int j0 = jt * 128;
    const int t  = threadIdx.x;
    const int lane = t & 63, wid = t >> 6;
    const int wr = wid >> 1, wc = wid & 1;

    __shared__ alignas(16) char lds[32768];  // Ah@0 | Al@8K | Bh@16K | Bl@24K, each [128][32]h16

    const size_t arow = ((size_t)b * LROWS + i0) * 256;
    const h16* bHp; const h16* bLp; size_t brow;
    if (isCorr) { bHp = Xh; bLp = Xl; brow = ((size_t)b * LROWS + j0) * 256; }
    else        { bHp = Wh; bLp = Xl; brow = (size_t)j0 * 256; }   // bLp unused for trans

    f32x4 acc[4][4];
#pragma unroll
    for (int i = 0; i < 4; ++i)
#pragma unroll
        for (int j = 0; j < 4; ++j) acc[i][j] = (f32x4){0.f, 0.f, 0.f, 0.f};

    const int grow = t >> 2;   // 0..63
    const int gq   = t & 3;    // 16B chunk within 64B row

    for (int kt = 0; kt < 8; ++kt) {
        __syncthreads();       // prior MFMA done reading LDS
#pragma unroll
        for (int p = 0; p < 2; ++p) {
            int r = p * 64 + grow;
            size_t so = (size_t)r * 256 + kt * 32 + ((gq ^ ((r >> 1) & 3)) << 3);
            char* d = lds + p * 4096 + wid * 1024;
            gl_lds16(Xh + arow + so, d);
            gl_lds16(Xl + arow + so, d + 8192);
            gl_lds16(bHp + brow + so, d + 16384);
            if (isCorr) gl_lds16(bLp + brow + so, d + 24576);
        }
        __syncthreads();       // drains global_load_lds

        const int kq = lane >> 4;
        const int rA = wr * 64 + (lane & 15);
        const int rB = wc * 64 + (lane & 15);
        h16x8 ah[4], al[4], bh[4], bl[4];
#pragma unroll
        for (int mi = 0; mi < 4; ++mi) {
            int r   = rA + mi * 16;
            int off = r * 64 + ((kq ^ ((r >> 1) & 3)) << 4);
            ah[mi] = *(const h16x8*)(lds + off);
            al[mi] = *(const h16x8*)(lds + 8192 + off);
        }
#pragma unroll
        for (int nj = 0; nj < 4; ++nj) {
            int r   = rB + nj * 16;
            int off = r * 64 + ((kq ^ ((r >> 1) & 3)) << 4);
            bh[nj] = *(const h16x8*)(lds + 16384 + off);
            if (isCorr) bl[nj] = *(const h16x8*)(lds + 24576 + off);
        }
        __builtin_amdgcn_s_setprio(1);
#pragma unroll
        for (int mi = 0; mi < 4; ++mi)
#pragma unroll
            for (int nj = 0; nj < 4; ++nj) {
                acc[mi][nj] = __builtin_amdgcn_mfma_f32_16x16x32_f16(ah[mi], bh[nj], acc[mi][nj], 0, 0, 0);
                acc[mi][nj] = __builtin_amdgcn_mfma_f32_16x16x32_f16(al[mi], bh[nj], acc[mi][nj], 0, 0, 0);
                if (isCorr)
                    acc[mi][nj] = __builtin_amdgcn_mfma_f32_16x16x32_f16(ah[mi], bl[nj], acc[mi][nj], 0, 0, 0);
            }
        __builtin_amdgcn_s_setprio(0);
    }

    const int mBase = i0 + wr * 64;
    const int nBase = j0 + wc * 64;
    if (isCorr) {
        h16* Pb = Ptil + (size_t)b * LROWS * 1024;
        // normal orientation: stats + p_tilde (rows i-range, chunk jt*2+wc)
        {
            const int chunk = jt * 2 + wc;
#pragma unroll
            for (int mi = 0; mi < 4; ++mi)
#pragma unroll
                for (int rg = 0; rg < 4; ++rg) {
                    float v0 = acc[mi][0][rg], v1 = acc[mi][1][rg];
                    float v2 = acc[mi][2][rg], v3 = acc[mi][3][rg];
                    float mx = fmaxf(fmaxf(v0, v1), fmaxf(v2, v3));
#pragma unroll
                    for (int off = 8; off >= 1; off >>= 1) mx = fmaxf(mx, __shfl_xor(mx, off, 64));
                    float e0 = __expf(v0 - mx), e1 = __expf(v1 - mx);
                    float e2 = __expf(v2 - mx), e3 = __expf(v3 - mx);
                    float s = e0 + e1 + e2 + e3;
#pragma unroll
                    for (int off = 8; off >= 1; off >>= 1) s += __shfl_xor(s, off, 64);
                    int row = mBase + mi * 16 + ((lane >> 4) * 4) + rg;
                    if ((lane & 15) == 0)
                        part[((size_t)b * 1024 + row) * 16 + chunk] = make_float2(mx, s);
                    size_t rb = (size_t)row * 1024 + nBase + (lane & 15);
                    Pb[rb]      = (h16)e0;
                    Pb[rb + 16] = (h16)e1;
                    Pb[rb + 32] = (h16)e2;
                    Pb[rb + 48] = (h16)e3;
                }
        }
        if (it != jt) {
            // transposed orientation: rows j-range (n), chunk in i-range
            const int chunk = it * 2 + wr;
#pragma unroll
            for (int nj = 0; nj < 4; ++nj) {
                float mx = -3.0e38f;
#pragma unroll
                for (int mi = 0; mi < 4; ++mi)
#pragma unroll
                    for (int rg = 0; rg < 4; ++rg) mx = fmaxf(mx, acc[mi][nj][rg]);
                mx = fmaxf(mx, __shfl_xor(mx, 16, 64));
                mx = fmaxf(mx, __shfl_xor(mx, 32, 64));
                float s = 0.f;
                h16x4 pt[4];
#pragma unroll
                for (int mi = 0; mi < 4; ++mi)
#pragma unroll
                    for (int rg = 0; rg < 4; ++rg) {
                        float e = __expf(acc[mi][nj][rg] - mx);
                        s += e;
                        pt[mi][rg] = (h16)e;
                    }
                s += __shfl_xor(s, 16, 64);
                s += __shfl_xor(s, 32, 64);
                int n = nBase + nj * 16 + (lane & 15);
                if (lane < 16)
                    part[((size_t)b * 1024 + n) * 16 + chunk] = make_float2(mx, s);
                size_t nb = (size_t)n * 1024 + mBase + ((lane >> 4) * 4);
#pragma unroll
                for (int mi = 0; mi < 4; ++mi)
                    *(h16x4*)(Pb + nb + mi * 16) = pt[mi];
            }
        }
    } else {
        // store t transposed, plain fp16
#pragma unroll
        for (int mi = 0; mi < 4; ++mi)
#pragma unroll
            for (int nj = 0; nj < 4; ++nj) {
                int n  = nBase + nj * 16 + (lane & 15);
                int m0 = mBase + mi * 16 + ((lane >> 4) * 4);
                h16x4 hv;
#pragma unroll
                for (int rg = 0; rg < 4; ++rg) hv[rg] = (h16)acc[mi][nj][rg];
                size_t off = ((size_t)b * 256 + n) * 1024 + m0;  // tT[b][g][l]
                *(h16x4*)(Th + off) = hv;
            }
    }
}

// ---------- PV: p = p_tilde * exp(m_chunk - M)/S; At=p (fp32); Node = relu(x + p·t) ----------
// M-tile 32, N full 256 (4 waves x 64-col quadrants), K=1024, Kt=64. 512 blocks, 4/CU.
__global__ __launch_bounds__(256, 4) void gemm_pv(
    const h16* __restrict__ Ptil, const float2* __restrict__ part,
    float* __restrict__ At,
    const h16* __restrict__ Th,
    h16* __restrict__ Xh, h16* __restrict__ Xl,
    float* __restrict__ NodeOut, float* __restrict__ OutBase, int last) {
    const int id   = blockIdx.x;
    const int xcd  = id & 7, rest = id >> 3;       // 512 blocks
    const int b    = (xcd << 1) | (rest & 1);      // same-b blocks share HW XCD -> tT in L2
    const int mt   = rest >> 1;                    // 0..31
    const int i0   = mt * 32;
    const int t    = threadIdx.x;
    const int lane = t & 63, wid = t >> 6;
    const int wc   = wid;                          // n-quadrant 0..3

    __shared__ alignas(16) char lds[38912];
    // A [32][64]h16 @0 (4K, swizzled) | B [256][64]h16 @4096 (32K) | sc [32][16]f32 @36864 (2K)
    float* sc = (float*)(lds + 36864);

    // stats prologue: per-row M,S then per-(row,chunk) scale
    if (t < 32) {
        const float2* pp = part + ((size_t)b * 1024 + i0 + t) * 16;
        float2 v[16];
        float M = -3.0e38f;
#pragma unroll
        for (int c = 0; c < 16; ++c) { v[c] = pp[c]; M = fmaxf(M, v[c].x); }
        float S = 0.f;
#pragma unroll
        for (int c = 0; c < 16; ++c) S += v[c].y * __expf(v[c].x - M);
        float inv = 1.0f / S;
#pragma unroll
        for (int c = 0; c < 16; ++c) sc[t * 16 + c] = __expf(v[c].x - M) * inv;
    }
    __syncthreads();

    const h16* Prow = Ptil + ((size_t)b * LROWS + i0) * 1024;
    float* Arow = At + ((size_t)b * LROWS + i0) * 1024;
    const size_t tbase = (size_t)b * 256 * 1024;

    const int ar = t >> 3;       // 0..31 (A row / B row-group)
    const int ac = t & 7;        // 8-col group

    f32x4 acc[2][4];
#pragma unroll
    for (int i = 0; i < 2; ++i)
#pragma unroll
        for (int j = 0; j < 4; ++j) acc[i][j] = (f32x4){0.f, 0.f, 0.f, 0.f};

    for (int kt = 0; kt < 16; ++kt) {
        // A: p_tilde fp16 load + per-chunk scale (global/LDS-sc reads — before barrier is fine)
        h16x8 pt = *(const h16x8*)(Prow + (size_t)ar * 1024 + kt * 64 + ac * 8);
        float s  = sc[ar * 16 + kt];
        __syncthreads();         // prior MFMA done reading LDS A/B

        // B: async global->LDS, pre-swizzled per-lane source, linear dest
#pragma unroll
        for (int itr = 0; itr < 8; ++itr) {
            int g = itr * 32 + ar;
            size_t so = tbase + (size_t)g * 1024 + kt * 64 + ((ac ^ (g & 7)) << 3);
            char* d = lds + 4096 + itr * 4096 + wid * 1024;
            gl_lds16(Th + so, d);
        }

        // normalize: write fp32 attn to d_out, stage fp16 product to LDS
        f32x4 plo, phi;
#pragma unroll
        for (int e = 0; e < 4; ++e) plo[e] = (float)pt[e] * s;
#pragma unroll
        for (int e = 0; e < 4; ++e) phi[e] = (float)pt[4 + e] * s;
        *(f32x4*)(Arow + (size_t)ar * 1024 + kt * 64 + ac * 8)     = plo;
        *(f32x4*)(Arow + (size_t)ar * 1024 + kt * 64 + ac * 8 + 4) = phi;
        h16x8 a16;
#pragma unroll
        for (int e = 0; e < 4; ++e) { a16[e] = (h16)plo[e]; a16[4 + e] = (h16)phi[e]; }
        *(h16x8*)(lds + ar * 128 + ((ac ^ (ar & 7)) << 4)) = a16;
        __syncthreads();         // drains ds_writes + global_load_lds

        const int kq = lane >> 4;
        __builtin_amdgcn_s_setprio(1);
#pragma unroll
        for (int s2 = 0; s2 < 2; ++s2) {
            h16x8 ah[2], bh[4];
#pragma unroll
            for (int mi = 0; mi < 2; ++mi) {
                int r = mi * 16 + (lane & 15);
                ah[mi] = *(const h16x8*)(lds + r * 128 + (((s2 * 4 + kq) ^ (r & 7)) << 4));
            }
#pragma unroll
            for (int nf = 0; nf < 4; ++nf) {
                int g = wc * 64 + nf * 16 + (lane & 15);
                bh[nf] = *(const h16x8*)(lds + 4096 + g * 128 + (((s2 * 4 + kq) ^ (g & 7)) << 4));
            }
#pragma unroll
            for (int mi = 0; mi < 2; ++mi)
#pragma unroll
                for (int nf = 0; nf < 4; ++nf)
                    acc[mi][nf] = __builtin_amdgcn_mfma_f32_16x16x32_f16(ah[mi], bh[nf], acc[mi][nf], 0, 0, 0);
        }
        __builtin_amdgcn_s_setprio(0);
    }

    // epilogue: residual + relu, update x hi/lo, write node (+final slices)
#pragma unroll
    for (int mi = 0; mi < 2; ++mi)
#pragma unroll
        for (int nf = 0; nf < 4; ++nf) {
            int n = wc * 64 + nf * 16 + (lane & 15);
#pragma unroll
            for (int rg = 0; rg < 4; ++rg) {
                int m = i0 + mi * 16 + ((lane >> 4) * 4) + rg;
                size_t off = ((size_t)b * LROWS + m) * FDIM + n;
                float res = (float)Xh[off] + (float)Xl[off];
                float y   = res + acc[mi][nf][rg];
                y = y > 0.f ? y : 0.f;
                NodeOut[off] = y;
                h16 hh, ll; split2(y, hh, ll);
                Xh[off] = hh; Xl[off] = ll;
                if (last) {
                    float* dst = (m < 256)
                        ? OutBase + OFF_TGT + ((size_t)b << 16) + ((size_t)m << 8) + n
                        : OutBase + OFF_CLM + (size_t)b * 196608 + ((size_t)(m - 256) << 8) + n;
                    *dst = y;
                }
            }
        }
}

// ---------- host ----------
extern "C" void kernel_launch(void* const* d_in, const int* in_sizes, int n_in,
                              void* d_out, int out_size, void* d_ws, size_t ws_size,
                              hipStream_t stream) {
    (void)in_sizes; (void)n_in; (void)out_size; (void)ws_size;
    const float* tgt = (const float*)d_in[0];
    const float* clm = (const float*)d_in[1];
    // d_in[2] = batch_adj: unused by the reference computation
    const float* W   = (const float*)d_in[3];
    float* out = (float*)d_out;
    char*  ws  = (char*)d_ws;

    h16* xh = (h16*)(ws);                            // 8 MB
    h16* xl = (h16*)(ws + (8ull << 20));             // 8 MB
    h16* th = (h16*)(ws + (16ull << 20));            // 8 MB
    h16* wh = (h16*)(ws + (24ull << 20));            // 384 KB
    float2* part = (float2*)(ws + (25ull << 20));    // 2 MB
    h16* ptil = (h16*)(ws + (27ull << 20));          // 32 MB: p_tilde fp16 [16][1024][1024]

    convert_all<<<4288, 256, 0, stream>>>(tgt, clm, W, xh, xl, wh);

    for (int L = 0; L < 3; ++L) {
        float* at = out + OFF_AT + (size_t)L * 16777216ull;
        float* nr = out + OFF_NR + (size_t)L * 4194304ull;
        gemm_ct<<<832, 256, 0, stream>>>(xh, xl, wh + (size_t)L * 65536, ptil, part, th);
        gemm_pv<<<512, 256, 0, stream>>>(ptil, part, at, th, xh, xl, nr, out, L == 2);
    }
}